// Round 4
// baseline (515.519 us; speedup 1.0000x reference)
//
#include <hip/hip_runtime.h>
#include <math.h>

#define Bb   4
#define Ss   16
#define Nn   2048
#define Ff   32
#define Ee   16384
#define EFf  8
#define Hh   64
#define HB2  32
#define E2c  (Ee + Nn)          // 18432
#define RTOT (Bb*Ss*Nn)         // 131072 (64 graphs x 2048)
#define Mm   (Ss*Nn)            // 32768
#define CST  68                 // cbuf row stride (64 cols + pad)

typedef __attribute__((ext_vector_type(8))) short short8;
typedef __attribute__((ext_vector_type(4))) float f32x4;
#define MFMA16 __builtin_amdgcn_mfma_f32_16x16x32_bf16

__device__ __forceinline__ float sigf(float x) { return 1.f / (1.f + __expf(-x)); }
__device__ __forceinline__ float tanhfast(float x) { return 2.f / (1.f + __expf(-2.f * x)) - 1.f; }

__device__ __forceinline__ void split_bf16(float x, unsigned short& h, unsigned short& l) {
  unsigned u = __float_as_uint(x);
  unsigned r = (u + 0x7FFFu + ((u >> 16) & 1u)) >> 16;
  h = (unsigned short)r;
  float rest = x - __uint_as_float(r << 16);
  unsigned u2 = __float_as_uint(rest);
  l = (unsigned short)((u2 + 0x7FFFu + ((u2 >> 16) & 1u)) >> 16);
}

template <int PAT>
__device__ __forceinline__ float xorf(float v) {
  return __int_as_float(__builtin_amdgcn_ds_swizzle(__float_as_int(v), PAT));
}
__device__ __forceinline__ float red8(float v) {
  int x = __builtin_amdgcn_update_dpp(0, __float_as_int(v), 0x128, 0xF, 0xF, true);
  v += __int_as_float(x);
  v += xorf<0x401F>(v);
  v += __shfl_xor(v, 32, 64);
  return v;
}
__device__ __forceinline__ float redlogit(float v) {
  int x;
  x = __builtin_amdgcn_update_dpp(0, __float_as_int(v), 0xB1, 0xF, 0xF, true);
  v += __int_as_float(x);
  x = __builtin_amdgcn_update_dpp(0, __float_as_int(v), 0x4E, 0xF, 0xF, true);
  v += __int_as_float(x);
  v += xorf<0x101F>(v);
  return v;
}

// ---------------------------------------------------------------------------
__global__ __launch_bounds__(256) void k_loop_accum(
    const int* __restrict__ ei, const float* __restrict__ ea,
    float* __restrict__ cntF, float* __restrict__ loopA) {
  int idx = blockIdx.x * 256 + threadIdx.x;
  int e = idx >> 3, j = idx & 7;
  int d = ei[Ee + e];
  atomicAdd(&loopA[d * EFf + j], ea[idx]);
  if (j == 0) atomicAdd(&cntF[d], 1.0f);
}

// ---------------------------------------------------------------------------
__global__ __launch_bounds__(256) void k_scan(
    const float* __restrict__ cntF, int* __restrict__ offs) {
  __shared__ int partial[256];
  int tid = threadIdx.x;
  int base = tid * 8;
  int vals[8];
  int s = 0;
  for (int i = 0; i < 8; ++i) {
    int c = (int)cntF[base + i] + 1;
    vals[i] = c;
    s += c;
  }
  partial[tid] = s;
  __syncthreads();
  for (int off = 1; off < 256; off <<= 1) {
    int v = partial[tid];
    int add = (tid >= off) ? partial[tid - off] : 0;
    __syncthreads();
    partial[tid] = v + add;
    __syncthreads();
  }
  int run = (tid == 0) ? 0 : partial[tid - 1];
  for (int i = 0; i < 8; ++i) {
    offs[base + i] = run;
    run += vals[i];
  }
  if (tid == 255) offs[Nn] = run;
}

__global__ __launch_bounds__(256) void k_scatter(
    const int* __restrict__ ei, const int* __restrict__ offs,
    int* __restrict__ fillI, int* __restrict__ posOf, int* __restrict__ srcA) {
  int e = blockIdx.x * 256 + threadIdx.x;
  if (e >= E2c) return;
  int d = (e < Ee) ? ei[Ee + e] : (e - Ee);
  int s = (e < Ee) ? ei[e]      : (e - Ee);
  int pos = offs[d] + atomicAdd(&fillI[d], 1);
  posOf[e] = pos;
  srcA[pos] = s;
}

// ---------------------------------------------------------------------------
// Pre-split + pre-swizzle weights into MFMA B-fragment order (R9 layout).
// ---------------------------------------------------------------------------
__global__ __launch_bounds__(256) void k_wprep(
    const float* __restrict__ Wl, const float* __restrict__ Wr,
    const float* __restrict__ Wih, const float* __restrict__ Whh,
    unsigned short* __restrict__ WXhi, unsigned short* __restrict__ WXlo,
    unsigned short* __restrict__ WGhi, unsigned short* __restrict__ WGlo) {
  int idx = blockIdx.x * 256 + threadIdx.x;   // 65536 total
  if (idx < 16384) {
    int j = idx & 7, lane = (idx >> 3) & 63, kh = (idx >> 9) & 1;
    int t = (idx >> 10) & 7, l = idx >> 13;
    int n = t * 16 + (lane & 15);
    int k = kh * 32 + ((lane >> 4) << 3) + j;
    const float* W = (n < 64) ? (Wl + (size_t)l * 4096) : (Wr + (size_t)l * 4096);
    float v = W[k * 64 + (n & 63)];
    unsigned short h, lo;
    split_bf16(v, h, lo);
    WXhi[idx] = h; WXlo[idx] = lo;
  } else {
    int i2 = idx - 16384;                     // < 49152
    int j = i2 & 7, lane = (i2 >> 3) & 63, kh = (i2 >> 9) & 1;
    int t = (i2 >> 10) % 24, l = i2 / 24576;
    int n = t * 16 + (lane & 15);
    int k = kh * 32 + ((lane >> 4) << 3) + j;
    int g = n >> 6, c = n & 63;
    const float* W = (g < 3) ? (Wih + (size_t)l * 12288 + (size_t)(g * 64 + c) * 64)
                             : (Whh + (size_t)l * 12288 + (size_t)((g - 3) * 64 + c) * 64);
    float v = W[k];
    unsigned short h, lo;
    split_bf16(v, h, lo);
    WGhi[i2] = h; WGlo[i2] = lo;
  }
}

// ---------------------------------------------------------------------------
// ep for BOTH layers; self-loop mean division folded in. blockIdx.y = layer.
// ---------------------------------------------------------------------------
__global__ __launch_bounds__(256) void k_ep(
    const float* __restrict__ ea, const float* __restrict__ loopA,
    const float* __restrict__ We, const int* __restrict__ posOf,
    const float* __restrict__ cntF, float* __restrict__ EPc) {
  __shared__ float wlds[EFf * Hh];
  int tid = threadIdx.x;
  int l = blockIdx.y;
  const float* Wel = We + (size_t)l * EFf * Hh;
  if (tid < EFf * Hh) wlds[tid] = Wel[tid];
  if (tid + 256 < EFf * Hh) wlds[tid + 256] = Wel[tid + 256];
  __syncthreads();
  int idx = blockIdx.x * 256 + tid;
  int e = idx >> 6, j = idx & 63;
  const float* a = (e < Ee) ? (ea + (size_t)e * EFf) : (loopA + (size_t)(e - Ee) * EFf);
  float acc = 0.f;
#pragma unroll
  for (int k = 0; k < EFf; ++k) acc += a[k] * wlds[k * Hh + j];
  if (e >= Ee) acc /= fmaxf(cntF[e - Ee], 1.0f);
  EPc[(size_t)l * E2c * Hh + (((size_t)posOf[e]) << 6) + j] = acc;
}

// ---------------------------------------------------------------------------
// proj (R5 version): thread = 2 rows x 16 cols. grid (RTOT/512, 4)
// ---------------------------------------------------------------------------
__global__ __launch_bounds__(256) void k_proj(
    const float* __restrict__ X, const float* __restrict__ Wp,
    const float* __restrict__ bp, float* __restrict__ Out) {
  __shared__ float w[32 * 16];
  int tid = threadIdx.x;
  int j0 = blockIdx.y << 4;
  for (int idx = tid; idx < 32 * 16; idx += 256)
    w[idx] = Wp[((idx >> 4) << 6) + j0 + (idx & 15)];
  __syncthreads();
  int r0 = (blockIdx.x << 9) + tid;
  float acc[2][16];
#pragma unroll
  for (int jj = 0; jj < 16; ++jj) { float b = bp[j0 + jj]; acc[0][jj] = b; acc[1][jj] = b; }
  const float* x0 = X + ((size_t)r0 << 5);
  const float* x1 = x0 + (256 << 5);
  for (int kc = 0; kc < 8; ++kc) {
    float4 a0 = *(const float4*)(x0 + 4 * kc);
    float4 a1 = *(const float4*)(x1 + 4 * kc);
    float a0a[4] = {a0.x, a0.y, a0.z, a0.w};
    float a1a[4] = {a1.x, a1.y, a1.z, a1.w};
#pragma unroll
    for (int q = 0; q < 4; ++q) {
      const float4* wp4 = (const float4*)(w + ((4 * kc + q) << 4));
#pragma unroll
      for (int q4 = 0; q4 < 4; ++q4) {
        float4 wv = wp4[q4];
        acc[0][4*q4+0] = fmaf(a0a[q], wv.x, acc[0][4*q4+0]);
        acc[0][4*q4+1] = fmaf(a0a[q], wv.y, acc[0][4*q4+1]);
        acc[0][4*q4+2] = fmaf(a0a[q], wv.z, acc[0][4*q4+2]);
        acc[0][4*q4+3] = fmaf(a0a[q], wv.w, acc[0][4*q4+3]);
        acc[1][4*q4+0] = fmaf(a1a[q], wv.x, acc[1][4*q4+0]);
        acc[1][4*q4+1] = fmaf(a1a[q], wv.y, acc[1][4*q4+1]);
        acc[1][4*q4+2] = fmaf(a1a[q], wv.z, acc[1][4*q4+2]);
        acc[1][4*q4+3] = fmaf(a1a[q], wv.w, acc[1][4*q4+3]);
      }
    }
  }
#pragma unroll
  for (int rr = 0; rr < 2; ++rr) {
    float* op = Out + (((size_t)(r0 + 256 * rr)) << 6) + j0;
#pragma unroll
    for (int q4 = 0; q4 < 4; ++q4)
      *(float4*)(op + 4 * q4) = make_float4(acc[rr][4*q4], acc[rr][4*q4+1], acc[rr][4*q4+2], acc[rr][4*q4+3]);
  }
}

// ---------------------------------------------------------------------------
// XL/XR via bf16x3 MFMA (R14, measured good).
// ---------------------------------------------------------------------------
__global__ __launch_bounds__(256) void k_xlr_mm(
    const float* __restrict__ X,
    const unsigned short* __restrict__ WXhi, const unsigned short* __restrict__ WXlo,
    const float* __restrict__ bl_, const float* __restrict__ br_,
    float* __restrict__ XL, float* __restrict__ XR) {
  __shared__ unsigned short ahi[4096], alo[4096];
  __shared__ float cbuf[64 * CST];
  int tid = threadIdx.x, lane = tid & 63, wv = tid >> 6;
  size_t m0 = (size_t)blockIdx.x << 6;
#pragma unroll
  for (int it = 0; it < 2; ++it) {
    int task = (it << 8) + tid;
    int row = task >> 3, cOct = task & 7;
    const float* src = X + ((m0 + row) << 6) + (cOct << 3);
    float4 a = *(const float4*)src;
    float4 b = *(const float4*)(src + 4);
    float va[8] = {a.x, a.y, a.z, a.w, b.x, b.y, b.z, b.w};
    short8 hv, lv;
#pragma unroll
    for (int j = 0; j < 8; ++j) {
      unsigned short hs, ls;
      split_bf16(va[j], hs, ls);
      hv[j] = (short)hs; lv[j] = (short)ls;
    }
    int f = ((cOct >> 2) * 4 + (row >> 4)) * 64 + ((cOct & 3) << 4) + (row & 15);
    *(short8*)&ahi[f << 3] = hv;
    *(short8*)&alo[f << 3] = lv;
  }
  __syncthreads();
  short8 Ah0 = *(const short8*)&ahi[((0 + wv) << 6 | lane) << 3];
  short8 Al0 = *(const short8*)&alo[((0 + wv) << 6 | lane) << 3];
  short8 Ah1 = *(const short8*)&ahi[((4 + wv) << 6 | lane) << 3];
  short8 Al1 = *(const short8*)&alo[((4 + wv) << 6 | lane) << 3];
  int nl = lane & 15;
  f32x4 acc[8];
#pragma unroll
  for (int t = 0; t < 8; ++t) {
    int n = t * 16 + nl;
    float b = (n < 64) ? bl_[n] : br_[n - 64];
    acc[t] = (f32x4){b, b, b, b};
  }
#pragma unroll
  for (int t = 0; t < 8; ++t) {
    const short8* bh0p = (const short8*)(WXhi + ((t << 1) << 9)) + lane;
    const short8* bl0p = (const short8*)(WXlo + ((t << 1) << 9)) + lane;
    const short8* bh1p = (const short8*)(WXhi + (((t << 1) + 1) << 9)) + lane;
    const short8* bl1p = (const short8*)(WXlo + (((t << 1) + 1) << 9)) + lane;
    short8 bh0 = *bh0p, bl0 = *bl0p, bh1 = *bh1p, bl1 = *bl1p;
    acc[t] = MFMA16(Ah0, bh0, acc[t], 0, 0, 0);
    acc[t] = MFMA16(Ah0, bl0, acc[t], 0, 0, 0);
    acc[t] = MFMA16(Al0, bh0, acc[t], 0, 0, 0);
    acc[t] = MFMA16(Ah1, bh1, acc[t], 0, 0, 0);
    acc[t] = MFMA16(Ah1, bl1, acc[t], 0, 0, 0);
    acc[t] = MFMA16(Al1, bh1, acc[t], 0, 0, 0);
  }
  int rbase = (wv << 4) + ((lane >> 4) << 2);
#pragma unroll
  for (int half = 0; half < 2; ++half) {
    __syncthreads();
#pragma unroll
    for (int tt = 0; tt < 4; ++tt) {
      int t = (half << 2) + tt;
#pragma unroll
      for (int reg = 0; reg < 4; ++reg)
        cbuf[(rbase + reg) * CST + (tt << 4) + nl] = acc[t][reg];
    }
    __syncthreads();
    float* dst = half ? XR : XL;
#pragma unroll
    for (int i = 0; i < 4; ++i) {
      int idx = (i << 10) + (tid << 2);
      int row = idx >> 6, col = idx & 63;
      *(float4*)(dst + ((m0 + row) << 6) + col) = *(float4*)&cbuf[row * CST + col];
    }
  }
}

// ---------------------------------------------------------------------------
// GATv2 v7: block = (dst d, graph 16-group q). Wave handles 4 graphs
// (q*16+wv+4c). EP/srcA loads amortized over 4 chains; ~10 VMEM in flight.
// grid (Nn, 4).
// ---------------------------------------------------------------------------
__global__ __launch_bounds__(256) void k_gat(
    const float* __restrict__ XL, float* __restrict__ XR_HG,
    const float* __restrict__ EPc, const int* __restrict__ offs,
    const int* __restrict__ srcA,
    const float* __restrict__ att, const float* __restrict__ gbl) {
  int d = blockIdx.x;
  int q = blockIdx.y;
  int tid = threadIdx.x;
  int wv = tid >> 6, lane = tid & 63;
  int eSub = lane >> 3, hOct = lane & 7;
  int hb = hOct << 3;
  float at[8], gv[8];
  {
    float4 a0 = *(const float4*)(att + hb);
    float4 a1 = *(const float4*)(att + hb + 4);
    float4 g0v = *(const float4*)(gbl + hb);
    float4 g1v = *(const float4*)(gbl + hb + 4);
    at[0]=a0.x; at[1]=a0.y; at[2]=a0.z; at[3]=a0.w;
    at[4]=a1.x; at[5]=a1.y; at[6]=a1.z; at[7]=a1.w;
    gv[0]=g0v.x; gv[1]=g0v.y; gv[2]=g0v.z; gv[3]=g0v.w;
    gv[4]=g1v.x; gv[5]=g1v.y; gv[6]=g1v.z; gv[7]=g1v.w;
  }
  int p0 = offs[d], p1 = offs[d + 1];
  int nE = p1 - p0;
  int nCh = (nE + 7) >> 3;
  int gbase = (q << 4) + wv;
  size_t rowg[4];
  const float* Xg[4];
  float xr[4][8];
#pragma unroll
  for (int c = 0; c < 4; ++c) {
    int g = gbase + (c << 2);
    rowg[c] = ((size_t)(g * Nn + d)) << 6;
    Xg[c] = XL + (((size_t)g * Nn) << 6);
    float4 a = *(const float4*)(XR_HG + rowg[c] + hb);
    float4 b = *(const float4*)(XR_HG + rowg[c] + hb + 4);
    xr[c][0]=a.x; xr[c][1]=a.y; xr[c][2]=a.z; xr[c][3]=a.w;
    xr[c][4]=b.x; xr[c][5]=b.y; xr[c][6]=b.z; xr[c][7]=b.w;
  }
  float Sd[4] = {0.f, 0.f, 0.f, 0.f};
  float acc[4][8];
#pragma unroll
  for (int c = 0; c < 4; ++c)
#pragma unroll
    for (int j = 0; j < 8; ++j) acc[c][j] = 0.f;

  for (int ck = 0; ck < nCh; ++ck) {
    int p = (ck << 3) + eSub;
    int pc = p < nE ? p : nE - 1;
    int s = srcA[p0 + pc];
    const float* epp = EPc + (((size_t)(p0 + pc)) << 6) + hb;
    float4 e0 = *(const float4*)epp;
    float4 e1 = *(const float4*)(epp + 4);
    float ep[8] = {e0.x, e0.y, e0.z, e0.w, e1.x, e1.y, e1.z, e1.w};
    float xlv[4][8];
#pragma unroll
    for (int c = 0; c < 4; ++c) {
      const float* xp = Xg[c] + ((size_t)s << 6) + hb;
      float4 x0 = *(const float4*)xp;
      float4 x1 = *(const float4*)(xp + 4);
      xlv[c][0]=x0.x; xlv[c][1]=x0.y; xlv[c][2]=x0.z; xlv[c][3]=x0.w;
      xlv[c][4]=x1.x; xlv[c][5]=x1.y; xlv[c][6]=x1.z; xlv[c][7]=x1.w;
    }
    float v[4] = {0.f, 0.f, 0.f, 0.f};
#pragma unroll
    for (int c = 0; c < 4; ++c)
#pragma unroll
      for (int j = 0; j < 8; ++j) {
        float m = xlv[c][j] + xr[c][j] + ep[j];
        m = fmaxf(m, 0.2f * m);
        v[c] = fmaf(m, at[j], v[c]);
      }
#pragma unroll
    for (int c = 0; c < 4; ++c) v[c] = redlogit(v[c]);
    bool live = (p < nE);
#pragma unroll
    for (int c = 0; c < 4; ++c) {
      float w = live ? __expf(v[c]) : 0.f;
      Sd[c] += w;
#pragma unroll
      for (int j = 0; j < 8; ++j) acc[c][j] = fmaf(w, xlv[c][j], acc[c][j]);
    }
  }
#pragma unroll
  for (int c = 0; c < 4; ++c) {
    Sd[c] = red8(Sd[c]);
#pragma unroll
    for (int j = 0; j < 8; ++j) acc[c][j] = red8(acc[c][j]);
  }
  if (eSub == 0) {
#pragma unroll
    for (int c = 0; c < 4; ++c) {
      float inv = 1.f / Sd[c];
      float* op = XR_HG + rowg[c] + hb;
      *(float4*)(op)     = make_float4(fmaf(acc[c][0], inv, gv[0]), fmaf(acc[c][1], inv, gv[1]),
                                       fmaf(acc[c][2], inv, gv[2]), fmaf(acc[c][3], inv, gv[3]));
      *(float4*)(op + 4) = make_float4(fmaf(acc[c][4], inv, gv[4]), fmaf(acc[c][5], inv, gv[5]),
                                       fmaf(acc[c][6], inv, gv[6]), fmaf(acc[c][7], inv, gv[7]));
    }
  }
}

// ---------------------------------------------------------------------------
// Fused GRU v3: 1-wave blocks, 32 rows/wave (2 row-tiles), grid Mm/32 = 1024.
// R3 counters showed the per-block serial t-chain IS the wall (doubling block
// count changed nothing; MfmaUtil 8.8%, VALU 24%, occ 10%). v3 removes the
// multi-wave barrier drains entirely (1 wave = free-running pipeline), halves
// L2 weight traffic (each weight fragment feeds 12 MFMAs via 2 row-tiles),
// and relieves VGPR pressure (launch_bounds(64,1): up to 512 VGPR, no spill;
// biases in LDS; h_prev blend reads cbuf in place).
// ---------------------------------------------------------------------------
__device__ __forceinline__ void mmtile(f32x4& a0, f32x4& a1,
    short8 Ah0, short8 Al0, short8 Ah1, short8 Al1,
    short8 Bh0, short8 Bl0, short8 Bh1, short8 Bl1,
    const unsigned short* __restrict__ Whi, const unsigned short* __restrict__ Wlo,
    int tt, int lane) {
  const short8* wh0p = (const short8*)(Whi + (tt << 10)) + lane;
  const short8* wl0p = (const short8*)(Wlo + (tt << 10)) + lane;
  const short8* wh1p = (const short8*)(Whi + (tt << 10) + 512) + lane;
  const short8* wl1p = (const short8*)(Wlo + (tt << 10) + 512) + lane;
  short8 h0 = *wh0p, l0 = *wl0p, h1 = *wh1p, l1 = *wl1p;
  a0 = MFMA16(Ah0, h0, a0, 0, 0, 0);
  a0 = MFMA16(Ah0, l0, a0, 0, 0, 0);
  a0 = MFMA16(Al0, h0, a0, 0, 0, 0);
  a0 = MFMA16(Ah1, h1, a0, 0, 0, 0);
  a0 = MFMA16(Ah1, l1, a0, 0, 0, 0);
  a0 = MFMA16(Al1, h1, a0, 0, 0, 0);
  a1 = MFMA16(Bh0, h0, a1, 0, 0, 0);
  a1 = MFMA16(Bh0, l0, a1, 0, 0, 0);
  a1 = MFMA16(Bl0, h0, a1, 0, 0, 0);
  a1 = MFMA16(Bh1, h1, a1, 0, 0, 0);
  a1 = MFMA16(Bh1, l1, a1, 0, 0, 0);
  a1 = MFMA16(Bl1, h1, a1, 0, 0, 0);
}

__global__ __launch_bounds__(64, 1) void k_gru_fused(
    const float* __restrict__ hgAll,
    const unsigned short* __restrict__ WGhi, const unsigned short* __restrict__ WGlo,
    const float* __restrict__ bih, const float* __restrict__ bhh,
    float* __restrict__ houtAll) {
  // frag buffers: group = kh*2 + rowtile (4 groups x 64 lane-slots x 8 shorts)
  __shared__ unsigned short ghi[2048], glo[2048], phi[2048], plo[2048];
  __shared__ float cbuf[32 * CST];
  __shared__ float blds[4 * 64];
  int lane = threadIdx.x;
  int nl = lane & 15;
  int rb0 = (lane >> 4) << 2;              // C-frag row base within a 16-tile
  size_t m0 = (size_t)blockIdx.x << 5;     // 32 rows/block

  // bias staging (R/Z fold bih+bhh; N/H separate for tanh(inn + r*hn))
  blds[lane]       = bih[lane]       + bhh[lane];
  blds[64 + lane]  = bih[64 + lane]  + bhh[64 + lane];
  blds[128 + lane] = bih[128 + lane];
  blds[192 + lane] = bhh[128 + lane];

  // t=0 prefetch: 256 row-octet tasks / 64 lanes = 4 its
  float4 pa[4], pb[4];
#pragma unroll
  for (int it = 0; it < 4; ++it) {
    int task = (it << 6) + lane;
    int row = task >> 3, cOct = task & 7;
    const float* srcg = hgAll + ((m0 + row) << 6) + (cOct << 3);
    pa[it] = *(const float4*)srcg;
    pb[it] = *(const float4*)(srcg + 4);
  }

  for (int t = 0; t < Bb; ++t) {
    // ---- stage G (from prefetched regs) → ghi/glo -------------------------
#pragma unroll
    for (int it = 0; it < 4; ++it) {
      int task = (it << 6) + lane;
      int row = task >> 3, cOct = task & 7;
      float va[8] = {pa[it].x, pa[it].y, pa[it].z, pa[it].w,
                     pb[it].x, pb[it].y, pb[it].z, pb[it].w};
      short8 hv8, lv8;
#pragma unroll
      for (int j = 0; j < 8; ++j) {
        unsigned short hs, ls;
        split_bf16(va[j], hs, ls);
        hv8[j] = (short)hs; lv8[j] = (short)ls;
      }
      int f = ((cOct >> 2) * 2 + (row >> 4)) * 64 + ((cOct & 3) << 4) + (row & 15);
      *(short8*)&ghi[f << 3] = hv8;
      *(short8*)&glo[f << 3] = lv8;
    }
    __syncthreads();   // single-wave: cheap; forces LDS write/read ordering

    // G frags: rg0 = groups {0,2}, rg1 = groups {1,3}
    short8 GAh0 = *(const short8*)&ghi[((0 << 6) | lane) << 3];
    short8 GAl0 = *(const short8*)&glo[((0 << 6) | lane) << 3];
    short8 GAh1 = *(const short8*)&ghi[((2 << 6) | lane) << 3];
    short8 GAl1 = *(const short8*)&glo[((2 << 6) | lane) << 3];
    short8 GBh0 = *(const short8*)&ghi[((1 << 6) | lane) << 3];
    short8 GBl0 = *(const short8*)&glo[((1 << 6) | lane) << 3];
    short8 GBh1 = *(const short8*)&ghi[((3 << 6) | lane) << 3];
    short8 GBl1 = *(const short8*)&glo[((3 << 6) | lane) << 3];

    // ---- prefetch next-t hg rows (latency hides under MFMAs) --------------
    if (t + 1 < Bb) {
      const float* hg = hgAll + (size_t)(t + 1) * ((size_t)Mm * Hh);
#pragma unroll
      for (int it = 0; it < 4; ++it) {
        int task = (it << 6) + lane;
        int row = task >> 3, cOct = task & 7;
        const float* srcg = hg + ((m0 + row) << 6) + (cOct << 3);
        pa[it] = *(const float4*)srcg;
        pb[it] = *(const float4*)(srcg + 4);
      }
    }

    // ---- MFMA: gi (and gh for t>0); acc[ct][rg], zero-init ---------------
    f32x4 accR[4][2], accZ[4][2], accN[4][2], accH[4][2];
#pragma unroll
    for (int ct = 0; ct < 4; ++ct) {
      accR[ct][0] = (f32x4){0.f, 0.f, 0.f, 0.f}; accR[ct][1] = (f32x4){0.f, 0.f, 0.f, 0.f};
      accZ[ct][0] = (f32x4){0.f, 0.f, 0.f, 0.f}; accZ[ct][1] = (f32x4){0.f, 0.f, 0.f, 0.f};
      accN[ct][0] = (f32x4){0.f, 0.f, 0.f, 0.f}; accN[ct][1] = (f32x4){0.f, 0.f, 0.f, 0.f};
      accH[ct][0] = (f32x4){0.f, 0.f, 0.f, 0.f}; accH[ct][1] = (f32x4){0.f, 0.f, 0.f, 0.f};
    }
#pragma unroll
    for (int ct = 0; ct < 4; ++ct) {
      mmtile(accR[ct][0], accR[ct][1], GAh0, GAl0, GAh1, GAl1,
             GBh0, GBl0, GBh1, GBl1, WGhi, WGlo, 0 + ct, lane);
      mmtile(accZ[ct][0], accZ[ct][1], GAh0, GAl0, GAh1, GAl1,
             GBh0, GBl0, GBh1, GBl1, WGhi, WGlo, 4 + ct, lane);
      mmtile(accN[ct][0], accN[ct][1], GAh0, GAl0, GAh1, GAl1,
             GBh0, GBl0, GBh1, GBl1, WGhi, WGlo, 8 + ct, lane);
    }
    if (t) {
      short8 PAh0 = *(const short8*)&phi[((0 << 6) | lane) << 3];
      short8 PAl0 = *(const short8*)&plo[((0 << 6) | lane) << 3];
      short8 PAh1 = *(const short8*)&phi[((2 << 6) | lane) << 3];
      short8 PAl1 = *(const short8*)&plo[((2 << 6) | lane) << 3];
      short8 PBh0 = *(const short8*)&phi[((1 << 6) | lane) << 3];
      short8 PBl0 = *(const short8*)&plo[((1 << 6) | lane) << 3];
      short8 PBh1 = *(const short8*)&phi[((3 << 6) | lane) << 3];
      short8 PBl1 = *(const short8*)&plo[((3 << 6) | lane) << 3];
#pragma unroll
      for (int ct = 0; ct < 4; ++ct) {
        mmtile(accR[ct][0], accR[ct][1], PAh0, PAl0, PAh1, PAl1,
               PBh0, PBl0, PBh1, PBl1, WGhi, WGlo, 12 + ct, lane);
        mmtile(accZ[ct][0], accZ[ct][1], PAh0, PAl0, PAh1, PAl1,
               PBh0, PBl0, PBh1, PBl1, WGhi, WGlo, 16 + ct, lane);
        mmtile(accH[ct][0], accH[ct][1], PAh0, PAl0, PAh1, PAl1,
               PBh0, PBl0, PBh1, PBl1, WGhi, WGlo, 20 + ct, lane);
      }
    }

    // ---- gates + h → cbuf (bias from LDS; h_prev read from cbuf in place) -
    {
      float bR[4], bZ[4], bN[4], bH[4];
#pragma unroll
      for (int ct = 0; ct < 4; ++ct) {
        int c = (ct << 4) + nl;
        bR[ct] = blds[c]; bZ[ct] = blds[64 + c];
        bN[ct] = blds[128 + c]; bH[ct] = blds[192 + c];
      }
#pragma unroll
      for (int rg = 0; rg < 2; ++rg) {
        int rbase = (rg << 4) + rb0;
#pragma unroll
        for (int ct = 0; ct < 4; ++ct) {
#pragma unroll
          for (int r = 0; r < 4; ++r) {
            float rgate = sigf(accR[ct][rg][r] + bR[ct]);
            float zg = sigf(accZ[ct][rg][r] + bZ[ct]);
            float ng = tanhfast(accN[ct][rg][r] + bN[ct] + rgate * (accH[ct][rg][r] + bH[ct]));
            int ci = (rbase + r) * CST + (ct << 4) + nl;
            float hp = t ? cbuf[ci] : 0.f;
            cbuf[ci] = (1.f - zg) * ng + zg * hp;
          }
        }
      }
    }
    __syncthreads();

    // ---- write h_out (coalesced) + restage h as P fragments ---------------
    float* hout = houtAll + (size_t)t * ((size_t)Mm * Hh);
#pragma unroll
    for (int i = 0; i < 8; ++i) {
      int idx = (i << 8) + (lane << 2);
      int row = idx >> 6, col = idx & 63;
      *(float4*)(hout + ((m0 + row) << 6) + col) = *(float4*)&cbuf[row * CST + col];
    }
    if (t + 1 < Bb) {
#pragma unroll
      for (int it = 0; it < 4; ++it) {
        int task = (it << 6) + lane;
        int row = task >> 3, cOct = task & 7;
        float4 q0 = *(const float4*)&cbuf[row * CST + (cOct << 3)];
        float4 q1 = *(const float4*)&cbuf[row * CST + (cOct << 3) + 4];
        float va[8] = {q0.x, q0.y, q0.z, q0.w, q1.x, q1.y, q1.z, q1.w};
        short8 hv8, lv8;
#pragma unroll
        for (int j = 0; j < 8; ++j) {
          unsigned short hs, ls;
          split_bf16(va[j], hs, ls);
          hv8[j] = (short)hs; lv8[j] = (short)ls;
        }
        int f = ((cOct >> 2) * 2 + (row >> 4)) * 64 + ((cOct & 3) << 4) + (row & 15);
        *(short8*)&phi[f << 3] = hv8;
        *(short8*)&plo[f << 3] = lv8;
      }
    }
  }
}

// ---------------------------------------------------------------------------
// Heads v2 (R17, measured good).
// ---------------------------------------------------------------------------
__global__ __launch_bounds__(256) void k_heads(
    const float* __restrict__ Xb,
    const float* __restrict__ oW1, const float* __restrict__ ob1,
    const float* __restrict__ oW2, const float* __restrict__ ob2,
    const float* __restrict__ dW1, const float* __restrict__ db1,
    const float* __restrict__ dW2, const float* __restrict__ db2,
    float* __restrict__ out) {
  __shared__ float xa[64 * 65];
  __shared__ float w1o[64 * 32], w1d[64 * 32];
  __shared__ float po[4][64], pd[4][64];
  int tid = threadIdx.x;
  int rblk = blockIdx.x << 6;
  int b = rblk >> 11;
  int n0 = rblk & (Nn - 1);
  const float* src = Xb + (((size_t)b * Ss + (Ss - 1)) * Nn + n0) * Hh;
#pragma unroll
  for (int i = 0; i < 4; ++i) {
    int idx = (i << 10) + (tid << 2);
    int row = idx >> 6, col = idx & 63;
    float4 v = *(const float4*)(src + idx);
    float* dp = &xa[row * 65 + col];
    dp[0] = v.x; dp[1] = v.y; dp[2] = v.z; dp[3] = v.w;
  }
  for (int idx = tid; idx < 2048; idx += 256) {
    w1o[idx] = oW1[idx];
    w1d[idx] = dW1[idx];
  }
  __syncthreads();
  int row = tid & 63;
  int jg = tid >> 6;
  int j0 = jg << 3;
  float hO[8], hD[8];
#pragma unroll
  for (int j = 0; j < 8; ++j) { hO[j] = ob1[j0 + j]; hD[j] = db1[j0 + j]; }
  const float* xr = &xa[row * 65];
  for (int k = 0; k < 64; ++k) {
    float xv = xr[k];
    const float4* wo = (const float4*)&w1o[(k << 5) + j0];
    const float4* wd = (const float4*)&w1d[(k << 5) + j0];
    float4 o0 = wo[0], o1 = wo[1], d0 = wd[0], d1 = wd[1];
    hO[0] = fmaf(xv, o0.x, hO[0]); hO[1] = fmaf(xv, o0.y, hO[1]);
    hO[2] = fmaf(xv, o0.z, hO[2]); hO[3] = fmaf(xv, o0.w, hO[3]);
    hO[4] = fmaf(xv, o1.x, hO[4]); hO[5] = fmaf(xv, o1.y, hO[5]);
    hO[6] = fmaf(xv, o1.z, hO[6]); hO[7] = fmaf(xv, o1.w, hO[7]);
    hD[0] = fmaf(xv, d0.x, hD[0]); hD[1] = fmaf(xv, d0.y, hD[1]);
    hD[2] = fmaf(xv, d0.z, hD[2]); hD[3] = fmaf(xv, d0.w, hD[3]);
    hD[4] = fmaf(xv, d1.x, hD[4]); hD[5] = fmaf(xv, d1.y, hD[5]);
    hD[6] = fmaf(xv, d1.z, hD[6]); hD[7] = fmaf(xv, d1.w, hD[7]);
  }
  float accoP = 0.f, accdP = 0.f;
#pragma unroll
  for (int j = 0; j < 8; ++j) {
    accoP = fmaf(fmaxf(hO[j], 0.f), oW2[j0 + j], accoP);
    accdP = fmaf(fmaxf(hD[j], 0.f), dW2[j0 + j], accdP);
  }
  po[jg][row] = accoP;
  pd[jg][row] = accdP;
  __syncthreads();
  if (tid < 64) {
    int r = rblk + tid;
    out[r]           = ob2[0] + ((po[0][tid] + po[1][tid]) + (po[2][tid] + po[3][tid]));
    out[Bb * Nn + r] = db2[0] + ((pd[0][tid] + pd[1][tid]) + (pd[2][tid] + pd[3][tid]));
  }
}

// ---------------------------------------------------------------------------
extern "C" void kernel_launch(void* const* d_in, const int* in_sizes, int n_in,
                              void* d_out, int out_size, void* d_ws, size_t ws_size,
                              hipStream_t stream) {
  const float* x   = (const float*)d_in[0];
  const int*   ei  = (const int*)d_in[1];
  const float* ea  = (const float*)d_in[2];
  const float* Wp  = (const float*)d_in[3];
  const float* bp  = (const float*)d_in[4];
  const float* Wl  = (const float*)d_in[5];
  const float* bl  = (const float*)d_in[6];
  const float* Wr  = (const float*)d_in[7];
  const float* br  = (const float*)d_in[8];
  const float* We  = (const float*)d_in[9];
  const float* att = (const float*)d_in[10];
  const float* gb  = (const float*)d_in[11];
  const float* Wih = (const float*)d_in[12];
  const float* Whh = (const float*)d_in[13];
  const float* bih = (const float*)d_in[14];
  const float* bhh = (const float*)d_in[15];
  const float* oW1 = (const float*)d_in[16];
  const float* ob1 = (const float*)d_in[17];
  const float* oW2 = (const float*)d_in[18];
  const float* ob2 = (const float*)d_in[19];
  const float* dW1 = (const float*)d_in[20];
  const float* db1 = (const float*)d_in[21];
  const float* dW2 = (const float*)d_in[22];
  const float* db2 = (const float*)d_in[23];
  float* out = (float*)d_out;

  // workspace layout
  float* f    = (float*)d_ws;
  float* Xb   = f;                          // RTOT*64
  float* XLb  = Xb  + (size_t)RTOT * Hh;
  float* XRb  = XLb + (size_t)RTOT * Hh;    // hg after k_gat
  float* EPc  = XRb + (size_t)RTOT * Hh;    // 2 * E2c * 64 (CSR order, both layers)
  unsigned short* WXhi = (unsigned short*)(EPc + (size_t)2 * E2c * Hh); // 16384
  unsigned short* WXlo = WXhi + 16384;
  unsigned short* WGhi = WXlo + 16384;      // 49152
  unsigned short* WGlo = WGhi + 49152;
  float* cntF = (float*)(WGlo + 49152);     // 2048
  float* loopA = cntF + Nn;                 // 2048*8
  int*   fillI = (int*)(loopA + Nn * EFf);  // 2048
  int*   offs  = fillI + Nn;                // 2049 (+pad)
  int*   posOf = offs + 2052;               // 18432
  int*   srcA  = posOf + E2c;               // 18432

  hipMemsetAsync(cntF, 0, (size_t)(Nn + Nn * EFf + Nn) * 4, stream);

  k_loop_accum<<<dim3(Ee * EFf / 256), 256, 0, stream>>>(ei, ea, cntF, loopA);
  k_scan<<<1, 256, 0, stream>>>(cntF, offs);
  k_scatter<<<dim3((E2c + 255) / 256), 256, 0, stream>>>(ei, offs, fillI, posOf, srcA);
  k_wprep<<<dim3(256), 256, 0, stream>>>(Wl, Wr, Wih, Whh, WXhi, WXlo, WGhi, WGlo);

  // X = x @ Wp + bp
  k_proj<<<dim3(RTOT / 512, 4), 256, 0, stream>>>(x, Wp, bp, Xb);

  // ep for both layers (division by cnt folded in)
  k_ep<<<dim3(E2c * Hh / 256, 2), 256, 0, stream>>>(ea, loopA, We, posOf, cntF, EPc);

  for (int l = 0; l < 2; ++l) {
    k_xlr_mm<<<dim3(RTOT / 64), 256, 0, stream>>>(
        Xb, WXhi + (size_t)l * 8192, WXlo + (size_t)l * 8192,
        bl + (size_t)l * Hh, br + (size_t)l * Hh, XLb, XRb);
    k_gat<<<dim3(Nn, 4), 256, 0, stream>>>(
        XLb, XRb, EPc + (size_t)l * E2c * Hh, offs, srcA,
        att + (size_t)l * Hh, gb + (size_t)l * Hh);
    k_gru_fused<<<dim3(Mm / 32), 64, 0, stream>>>(
        XRb, WGhi + (size_t)l * 24576, WGlo + (size_t)l * 24576,
        bih + (size_t)l * 192, bhh + (size_t)l * 192, Xb);
  }

  k_heads<<<dim3(Bb * Nn / 64), 256, 0, stream>>>(
      Xb, oW1, ob1, oW2, ob2, dW1, db1, dW2, db2, out);
}

// Round 5
// 395.668 us; speedup vs baseline: 1.3029x; 1.3029x over previous
//
#include <hip/hip_runtime.h>
#include <math.h>

#define Bb   4
#define Ss   16
#define Nn   2048
#define Ff   32
#define Ee   16384
#define EFf  8
#define Hh   64
#define HB2  32
#define E2c  (Ee + Nn)          // 18432
#define RTOT (Bb*Ss*Nn)         // 131072 (64 graphs x 2048)
#define Mm   (Ss*Nn)            // 32768
#define CST  68                 // cbuf row stride (64 cols + pad)

typedef __attribute__((ext_vector_type(8))) short short8;
typedef __attribute__((ext_vector_type(4))) float f32x4;
#define MFMA16 __builtin_amdgcn_mfma_f32_16x16x32_bf16

__device__ __forceinline__ float sigf(float x) { return 1.f / (1.f + __expf(-x)); }
__device__ __forceinline__ float tanhfast(float x) { return 2.f / (1.f + __expf(-2.f * x)) - 1.f; }

__device__ __forceinline__ void split_bf16(float x, unsigned short& h, unsigned short& l) {
  unsigned u = __float_as_uint(x);
  unsigned r = (u + 0x7FFFu + ((u >> 16) & 1u)) >> 16;
  h = (unsigned short)r;
  float rest = x - __uint_as_float(r << 16);
  unsigned u2 = __float_as_uint(rest);
  l = (unsigned short)((u2 + 0x7FFFu + ((u2 >> 16) & 1u)) >> 16);
}

template <int PAT>
__device__ __forceinline__ float xorf(float v) {
  return __int_as_float(__builtin_amdgcn_ds_swizzle(__float_as_int(v), PAT));
}
__device__ __forceinline__ float red8(float v) {
  int x = __builtin_amdgcn_update_dpp(0, __float_as_int(v), 0x128, 0xF, 0xF, true);
  v += __int_as_float(x);
  v += xorf<0x401F>(v);
  v += __shfl_xor(v, 32, 64);
  return v;
}
__device__ __forceinline__ float redlogit(float v) {
  int x;
  x = __builtin_amdgcn_update_dpp(0, __float_as_int(v), 0xB1, 0xF, 0xF, true);
  v += __int_as_float(x);
  x = __builtin_amdgcn_update_dpp(0, __float_as_int(v), 0x4E, 0xF, 0xF, true);
  v += __int_as_float(x);
  v += xorf<0x101F>(v);
  return v;
}

// ---------------------------------------------------------------------------
__global__ __launch_bounds__(256) void k_loop_accum(
    const int* __restrict__ ei, const float* __restrict__ ea,
    float* __restrict__ cntF, float* __restrict__ loopA) {
  int idx = blockIdx.x * 256 + threadIdx.x;
  int e = idx >> 3, j = idx & 7;
  int d = ei[Ee + e];
  atomicAdd(&loopA[d * EFf + j], ea[idx]);
  if (j == 0) atomicAdd(&cntF[d], 1.0f);
}

// ---------------------------------------------------------------------------
__global__ __launch_bounds__(256) void k_scan(
    const float* __restrict__ cntF, int* __restrict__ offs) {
  __shared__ int partial[256];
  int tid = threadIdx.x;
  int base = tid * 8;
  int vals[8];
  int s = 0;
  for (int i = 0; i < 8; ++i) {
    int c = (int)cntF[base + i] + 1;
    vals[i] = c;
    s += c;
  }
  partial[tid] = s;
  __syncthreads();
  for (int off = 1; off < 256; off <<= 1) {
    int v = partial[tid];
    int add = (tid >= off) ? partial[tid - off] : 0;
    __syncthreads();
    partial[tid] = v + add;
    __syncthreads();
  }
  int run = (tid == 0) ? 0 : partial[tid - 1];
  for (int i = 0; i < 8; ++i) {
    offs[base + i] = run;
    run += vals[i];
  }
  if (tid == 255) offs[Nn] = run;
}

__global__ __launch_bounds__(256) void k_scatter(
    const int* __restrict__ ei, const int* __restrict__ offs,
    int* __restrict__ fillI, int* __restrict__ posOf, int* __restrict__ srcA) {
  int e = blockIdx.x * 256 + threadIdx.x;
  if (e >= E2c) return;
  int d = (e < Ee) ? ei[Ee + e] : (e - Ee);
  int s = (e < Ee) ? ei[e]      : (e - Ee);
  int pos = offs[d] + atomicAdd(&fillI[d], 1);
  posOf[e] = pos;
  srcA[pos] = s;
}

// ---------------------------------------------------------------------------
// Pre-split + pre-swizzle weights into MFMA B-fragment order (R9 layout).
// ---------------------------------------------------------------------------
__global__ __launch_bounds__(256) void k_wprep(
    const float* __restrict__ Wl, const float* __restrict__ Wr,
    const float* __restrict__ Wih, const float* __restrict__ Whh,
    unsigned short* __restrict__ WXhi, unsigned short* __restrict__ WXlo,
    unsigned short* __restrict__ WGhi, unsigned short* __restrict__ WGlo) {
  int idx = blockIdx.x * 256 + threadIdx.x;   // 65536 total
  if (idx < 16384) {
    int j = idx & 7, lane = (idx >> 3) & 63, kh = (idx >> 9) & 1;
    int t = (idx >> 10) & 7, l = idx >> 13;
    int n = t * 16 + (lane & 15);
    int k = kh * 32 + ((lane >> 4) << 3) + j;
    const float* W = (n < 64) ? (Wl + (size_t)l * 4096) : (Wr + (size_t)l * 4096);
    float v = W[k * 64 + (n & 63)];
    unsigned short h, lo;
    split_bf16(v, h, lo);
    WXhi[idx] = h; WXlo[idx] = lo;
  } else {
    int i2 = idx - 16384;                     // < 49152
    int j = i2 & 7, lane = (i2 >> 3) & 63, kh = (i2 >> 9) & 1;
    int t = (i2 >> 10) % 24, l = i2 / 24576;
    int n = t * 16 + (lane & 15);
    int k = kh * 32 + ((lane >> 4) << 3) + j;
    int g = n >> 6, c = n & 63;
    const float* W = (g < 3) ? (Wih + (size_t)l * 12288 + (size_t)(g * 64 + c) * 64)
                             : (Whh + (size_t)l * 12288 + (size_t)((g - 3) * 64 + c) * 64);
    float v = W[k];
    unsigned short h, lo;
    split_bf16(v, h, lo);
    WGhi[i2] = h; WGlo[i2] = lo;
  }
}

// ---------------------------------------------------------------------------
// ep for BOTH layers; self-loop mean division folded in. blockIdx.y = layer.
// ---------------------------------------------------------------------------
__global__ __launch_bounds__(256) void k_ep(
    const float* __restrict__ ea, const float* __restrict__ loopA,
    const float* __restrict__ We, const int* __restrict__ posOf,
    const float* __restrict__ cntF, float* __restrict__ EPc) {
  __shared__ float wlds[EFf * Hh];
  int tid = threadIdx.x;
  int l = blockIdx.y;
  const float* Wel = We + (size_t)l * EFf * Hh;
  if (tid < EFf * Hh) wlds[tid] = Wel[tid];
  if (tid + 256 < EFf * Hh) wlds[tid + 256] = Wel[tid + 256];
  __syncthreads();
  int idx = blockIdx.x * 256 + tid;
  int e = idx >> 6, j = idx & 63;
  const float* a = (e < Ee) ? (ea + (size_t)e * EFf) : (loopA + (size_t)(e - Ee) * EFf);
  float acc = 0.f;
#pragma unroll
  for (int k = 0; k < EFf; ++k) acc += a[k] * wlds[k * Hh + j];
  if (e >= Ee) acc /= fmaxf(cntF[e - Ee], 1.0f);
  EPc[(size_t)l * E2c * Hh + (((size_t)posOf[e]) << 6) + j] = acc;
}

// ---------------------------------------------------------------------------
// proj (R5 version): thread = 2 rows x 16 cols. grid (RTOT/512, 4)
// ---------------------------------------------------------------------------
__global__ __launch_bounds__(256) void k_proj(
    const float* __restrict__ X, const float* __restrict__ Wp,
    const float* __restrict__ bp, float* __restrict__ Out) {
  __shared__ float w[32 * 16];
  int tid = threadIdx.x;
  int j0 = blockIdx.y << 4;
  for (int idx = tid; idx < 32 * 16; idx += 256)
    w[idx] = Wp[((idx >> 4) << 6) + j0 + (idx & 15)];
  __syncthreads();
  int r0 = (blockIdx.x << 9) + tid;
  float acc[2][16];
#pragma unroll
  for (int jj = 0; jj < 16; ++jj) { float b = bp[j0 + jj]; acc[0][jj] = b; acc[1][jj] = b; }
  const float* x0 = X + ((size_t)r0 << 5);
  const float* x1 = x0 + (256 << 5);
  for (int kc = 0; kc < 8; ++kc) {
    float4 a0 = *(const float4*)(x0 + 4 * kc);
    float4 a1 = *(const float4*)(x1 + 4 * kc);
    float a0a[4] = {a0.x, a0.y, a0.z, a0.w};
    float a1a[4] = {a1.x, a1.y, a1.z, a1.w};
#pragma unroll
    for (int q = 0; q < 4; ++q) {
      const float4* wp4 = (const float4*)(w + ((4 * kc + q) << 4));
#pragma unroll
      for (int q4 = 0; q4 < 4; ++q4) {
        float4 wv = wp4[q4];
        acc[0][4*q4+0] = fmaf(a0a[q], wv.x, acc[0][4*q4+0]);
        acc[0][4*q4+1] = fmaf(a0a[q], wv.y, acc[0][4*q4+1]);
        acc[0][4*q4+2] = fmaf(a0a[q], wv.z, acc[0][4*q4+2]);
        acc[0][4*q4+3] = fmaf(a0a[q], wv.w, acc[0][4*q4+3]);
        acc[1][4*q4+0] = fmaf(a1a[q], wv.x, acc[1][4*q4+0]);
        acc[1][4*q4+1] = fmaf(a1a[q], wv.y, acc[1][4*q4+1]);
        acc[1][4*q4+2] = fmaf(a1a[q], wv.z, acc[1][4*q4+2]);
        acc[1][4*q4+3] = fmaf(a1a[q], wv.w, acc[1][4*q4+3]);
      }
    }
  }
#pragma unroll
  for (int rr = 0; rr < 2; ++rr) {
    float* op = Out + (((size_t)(r0 + 256 * rr)) << 6) + j0;
#pragma unroll
    for (int q4 = 0; q4 < 4; ++q4)
      *(float4*)(op + 4 * q4) = make_float4(acc[rr][4*q4], acc[rr][4*q4+1], acc[rr][4*q4+2], acc[rr][4*q4+3]);
  }
}

// ---------------------------------------------------------------------------
// XL/XR via bf16x3 MFMA (R14, measured good).
// ---------------------------------------------------------------------------
__global__ __launch_bounds__(256) void k_xlr_mm(
    const float* __restrict__ X,
    const unsigned short* __restrict__ WXhi, const unsigned short* __restrict__ WXlo,
    const float* __restrict__ bl_, const float* __restrict__ br_,
    float* __restrict__ XL, float* __restrict__ XR) {
  __shared__ unsigned short ahi[4096], alo[4096];
  __shared__ float cbuf[64 * CST];
  int tid = threadIdx.x, lane = tid & 63, wv = tid >> 6;
  size_t m0 = (size_t)blockIdx.x << 6;
#pragma unroll
  for (int it = 0; it < 2; ++it) {
    int task = (it << 8) + tid;
    int row = task >> 3, cOct = task & 7;
    const float* src = X + ((m0 + row) << 6) + (cOct << 3);
    float4 a = *(const float4*)src;
    float4 b = *(const float4*)(src + 4);
    float va[8] = {a.x, a.y, a.z, a.w, b.x, b.y, b.z, b.w};
    short8 hv, lv;
#pragma unroll
    for (int j = 0; j < 8; ++j) {
      unsigned short hs, ls;
      split_bf16(va[j], hs, ls);
      hv[j] = (short)hs; lv[j] = (short)ls;
    }
    int f = ((cOct >> 2) * 4 + (row >> 4)) * 64 + ((cOct & 3) << 4) + (row & 15);
    *(short8*)&ahi[f << 3] = hv;
    *(short8*)&alo[f << 3] = lv;
  }
  __syncthreads();
  short8 Ah0 = *(const short8*)&ahi[((0 + wv) << 6 | lane) << 3];
  short8 Al0 = *(const short8*)&alo[((0 + wv) << 6 | lane) << 3];
  short8 Ah1 = *(const short8*)&ahi[((4 + wv) << 6 | lane) << 3];
  short8 Al1 = *(const short8*)&alo[((4 + wv) << 6 | lane) << 3];
  int nl = lane & 15;
  f32x4 acc[8];
#pragma unroll
  for (int t = 0; t < 8; ++t) {
    int n = t * 16 + nl;
    float b = (n < 64) ? bl_[n] : br_[n - 64];
    acc[t] = (f32x4){b, b, b, b};
  }
#pragma unroll
  for (int t = 0; t < 8; ++t) {
    const short8* bh0p = (const short8*)(WXhi + ((t << 1) << 9)) + lane;
    const short8* bl0p = (const short8*)(WXlo + ((t << 1) << 9)) + lane;
    const short8* bh1p = (const short8*)(WXhi + (((t << 1) + 1) << 9)) + lane;
    const short8* bl1p = (const short8*)(WXlo + (((t << 1) + 1) << 9)) + lane;
    short8 bh0 = *bh0p, bl0 = *bl0p, bh1 = *bh1p, bl1 = *bl1p;
    acc[t] = MFMA16(Ah0, bh0, acc[t], 0, 0, 0);
    acc[t] = MFMA16(Ah0, bl0, acc[t], 0, 0, 0);
    acc[t] = MFMA16(Al0, bh0, acc[t], 0, 0, 0);
    acc[t] = MFMA16(Ah1, bh1, acc[t], 0, 0, 0);
    acc[t] = MFMA16(Ah1, bl1, acc[t], 0, 0, 0);
    acc[t] = MFMA16(Al1, bh1, acc[t], 0, 0, 0);
  }
  int rbase = (wv << 4) + ((lane >> 4) << 2);
#pragma unroll
  for (int half = 0; half < 2; ++half) {
    __syncthreads();
#pragma unroll
    for (int tt = 0; tt < 4; ++tt) {
      int t = (half << 2) + tt;
#pragma unroll
      for (int reg = 0; reg < 4; ++reg)
        cbuf[(rbase + reg) * CST + (tt << 4) + nl] = acc[t][reg];
    }
    __syncthreads();
    float* dst = half ? XR : XL;
#pragma unroll
    for (int i = 0; i < 4; ++i) {
      int idx = (i << 10) + (tid << 2);
      int row = idx >> 6, col = idx & 63;
      *(float4*)(dst + ((m0 + row) << 6) + col) = *(float4*)&cbuf[row * CST + col];
    }
  }
}

// ---------------------------------------------------------------------------
// GATv2 v7: block = (dst d, graph 16-group q). Wave handles 4 graphs
// (q*16+wv+4c). EP/srcA loads amortized over 4 chains; ~10 VMEM in flight.
// grid (Nn, 4).
// ---------------------------------------------------------------------------
__global__ __launch_bounds__(256) void k_gat(
    const float* __restrict__ XL, float* __restrict__ XR_HG,
    const float* __restrict__ EPc, const int* __restrict__ offs,
    const int* __restrict__ srcA,
    const float* __restrict__ att, const float* __restrict__ gbl) {
  int d = blockIdx.x;
  int q = blockIdx.y;
  int tid = threadIdx.x;
  int wv = tid >> 6, lane = tid & 63;
  int eSub = lane >> 3, hOct = lane & 7;
  int hb = hOct << 3;
  float at[8], gv[8];
  {
    float4 a0 = *(const float4*)(att + hb);
    float4 a1 = *(const float4*)(att + hb + 4);
    float4 g0v = *(const float4*)(gbl + hb);
    float4 g1v = *(const float4*)(gbl + hb + 4);
    at[0]=a0.x; at[1]=a0.y; at[2]=a0.z; at[3]=a0.w;
    at[4]=a1.x; at[5]=a1.y; at[6]=a1.z; at[7]=a1.w;
    gv[0]=g0v.x; gv[1]=g0v.y; gv[2]=g0v.z; gv[3]=g0v.w;
    gv[4]=g1v.x; gv[5]=g1v.y; gv[6]=g1v.z; gv[7]=g1v.w;
  }
  int p0 = offs[d], p1 = offs[d + 1];
  int nE = p1 - p0;
  int nCh = (nE + 7) >> 3;
  int gbase = (q << 4) + wv;
  size_t rowg[4];
  const float* Xg[4];
  float xr[4][8];
#pragma unroll
  for (int c = 0; c < 4; ++c) {
    int g = gbase + (c << 2);
    rowg[c] = ((size_t)(g * Nn + d)) << 6;
    Xg[c] = XL + (((size_t)g * Nn) << 6);
    float4 a = *(const float4*)(XR_HG + rowg[c] + hb);
    float4 b = *(const float4*)(XR_HG + rowg[c] + hb + 4);
    xr[c][0]=a.x; xr[c][1]=a.y; xr[c][2]=a.z; xr[c][3]=a.w;
    xr[c][4]=b.x; xr[c][5]=b.y; xr[c][6]=b.z; xr[c][7]=b.w;
  }
  float Sd[4] = {0.f, 0.f, 0.f, 0.f};
  float acc[4][8];
#pragma unroll
  for (int c = 0; c < 4; ++c)
#pragma unroll
    for (int j = 0; j < 8; ++j) acc[c][j] = 0.f;

  for (int ck = 0; ck < nCh; ++ck) {
    int p = (ck << 3) + eSub;
    int pc = p < nE ? p : nE - 1;
    int s = srcA[p0 + pc];
    const float* epp = EPc + (((size_t)(p0 + pc)) << 6) + hb;
    float4 e0 = *(const float4*)epp;
    float4 e1 = *(const float4*)(epp + 4);
    float ep[8] = {e0.x, e0.y, e0.z, e0.w, e1.x, e1.y, e1.z, e1.w};
    float xlv[4][8];
#pragma unroll
    for (int c = 0; c < 4; ++c) {
      const float* xp = Xg[c] + ((size_t)s << 6) + hb;
      float4 x0 = *(const float4*)xp;
      float4 x1 = *(const float4*)(xp + 4);
      xlv[c][0]=x0.x; xlv[c][1]=x0.y; xlv[c][2]=x0.z; xlv[c][3]=x0.w;
      xlv[c][4]=x1.x; xlv[c][5]=x1.y; xlv[c][6]=x1.z; xlv[c][7]=x1.w;
    }
    float v[4] = {0.f, 0.f, 0.f, 0.f};
#pragma unroll
    for (int c = 0; c < 4; ++c)
#pragma unroll
      for (int j = 0; j < 8; ++j) {
        float m = xlv[c][j] + xr[c][j] + ep[j];
        m = fmaxf(m, 0.2f * m);
        v[c] = fmaf(m, at[j], v[c]);
      }
#pragma unroll
    for (int c = 0; c < 4; ++c) v[c] = redlogit(v[c]);
    bool live = (p < nE);
#pragma unroll
    for (int c = 0; c < 4; ++c) {
      float w = live ? __expf(v[c]) : 0.f;
      Sd[c] += w;
#pragma unroll
      for (int j = 0; j < 8; ++j) acc[c][j] = fmaf(w, xlv[c][j], acc[c][j]);
    }
  }
#pragma unroll
  for (int c = 0; c < 4; ++c) {
    Sd[c] = red8(Sd[c]);
#pragma unroll
    for (int j = 0; j < 8; ++j) acc[c][j] = red8(acc[c][j]);
  }
  if (eSub == 0) {
#pragma unroll
    for (int c = 0; c < 4; ++c) {
      float inv = 1.f / Sd[c];
      float* op = XR_HG + rowg[c] + hb;
      *(float4*)(op)     = make_float4(fmaf(acc[c][0], inv, gv[0]), fmaf(acc[c][1], inv, gv[1]),
                                       fmaf(acc[c][2], inv, gv[2]), fmaf(acc[c][3], inv, gv[3]));
      *(float4*)(op + 4) = make_float4(fmaf(acc[c][4], inv, gv[4]), fmaf(acc[c][5], inv, gv[5]),
                                       fmaf(acc[c][6], inv, gv[6]), fmaf(acc[c][7], inv, gv[7]));
    }
  }
}

// ---------------------------------------------------------------------------
// Fused GRU v4: weights staged in LDS ONCE per block (96 KB), killing the
// 786 MB/launch L2 weight re-stream that R3/R4 counters identified as the
// chain bottleneck. Block = 256 thr / 4 waves / 64 rows (v1's verified frag
// structure), grid Mm/64 = 512, 1 block/CU (129 KB LDS), 2 rounds.
// P-fragments are rebuilt per t directly from cbuf (intra-wave transpose of
// the wave's OWN rows) — phi/plo buffers and the restage pass removed.
// ---------------------------------------------------------------------------
__device__ __forceinline__ void mm6l(f32x4& acc,
    short8 Ah0, short8 Al0, short8 Ah1, short8 Al1,
    const unsigned short* Whi, const unsigned short* Wlo,
    int tt, int lane) {
  const short8* bh0p = (const short8*)(Whi + (tt << 10)) + lane;
  const short8* bl0p = (const short8*)(Wlo + (tt << 10)) + lane;
  const short8* bh1p = (const short8*)(Whi + (tt << 10) + 512) + lane;
  const short8* bl1p = (const short8*)(Wlo + (tt << 10) + 512) + lane;
  short8 bh0 = *bh0p, bl0 = *bl0p, bh1 = *bh1p, bl1 = *bl1p;
  acc = MFMA16(Ah0, bh0, acc, 0, 0, 0);
  acc = MFMA16(Ah0, bl0, acc, 0, 0, 0);
  acc = MFMA16(Al0, bh0, acc, 0, 0, 0);
  acc = MFMA16(Ah1, bh1, acc, 0, 0, 0);
  acc = MFMA16(Ah1, bl1, acc, 0, 0, 0);
  acc = MFMA16(Al1, bh1, acc, 0, 0, 0);
}

__global__ __launch_bounds__(256) void k_gru_fused(
    const float* __restrict__ hgAll,
    const unsigned short* __restrict__ WGhi, const unsigned short* __restrict__ WGlo,
    const float* __restrict__ bih, const float* __restrict__ bhh,
    float* __restrict__ houtAll) {
  __shared__ unsigned short whi[24576], wlo[24576];   // 96 KB weight frags
  __shared__ unsigned short ghi[4096], glo[4096];     // 16 KB input frags
  __shared__ float cbuf[64 * CST];                    // 17 KB h / output stage
  int tid = threadIdx.x, lane = tid & 63, wv = tid >> 6;
  int nl = lane & 15;
  int rbase = (wv << 4) + ((lane >> 4) << 2);
  size_t m0 = (size_t)blockIdx.x << 6;

  // ---- stage full weight fragment set into LDS (once) ---------------------
#pragma unroll
  for (int i = 0; i < 12; ++i) {
    int c = (i << 8) + tid;                           // 3072 short8 chunks
    *(short8*)&whi[c << 3] = *(const short8*)(WGhi + ((size_t)c << 3));
    *(short8*)&wlo[c << 3] = *(const short8*)(WGlo + ((size_t)c << 3));
  }

  // biases folded into acc init (R/Z get bih+bhh; N/H separate)
  float biasR[4], biasZ[4], biasN[4], biasH[4];
#pragma unroll
  for (int ct = 0; ct < 4; ++ct) {
    int c = (ct << 4) + nl;
    biasR[ct] = bih[c]       + bhh[c];
    biasZ[ct] = bih[64 + c]  + bhh[64 + c];
    biasN[ct] = bih[128 + c];
    biasH[ct] = bhh[128 + c];
  }

  // t=0 prefetch: 512 row-octet tasks / 256 thr = 2 its
  float4 pa[2], pb[2];
#pragma unroll
  for (int it = 0; it < 2; ++it) {
    int task = (it << 8) + tid;
    int row = task >> 3, cOct = task & 7;
    const float* srcg = hgAll + ((m0 + row) << 6) + (cOct << 3);
    pa[it] = *(const float4*)srcg;
    pb[it] = *(const float4*)(srcg + 4);
  }

  for (int t = 0; t < Bb; ++t) {
    // ---- stage G (from prefetched regs) → ghi/glo -------------------------
#pragma unroll
    for (int it = 0; it < 2; ++it) {
      int task = (it << 8) + tid;
      int row = task >> 3, cOct = task & 7;
      float va[8] = {pa[it].x, pa[it].y, pa[it].z, pa[it].w,
                     pb[it].x, pb[it].y, pb[it].z, pb[it].w};
      short8 hv8, lv8;
#pragma unroll
      for (int j = 0; j < 8; ++j) {
        unsigned short hs, ls;
        split_bf16(va[j], hs, ls);
        hv8[j] = (short)hs; lv8[j] = (short)ls;
      }
      int f = ((cOct >> 2) * 4 + (row >> 4)) * 64 + ((cOct & 3) << 4) + (row & 15);
      *(short8*)&ghi[f << 3] = hv8;
      *(short8*)&glo[f << 3] = lv8;
    }
    __syncthreads();   // A: ghi/glo ready (t=0: also weight staging complete)

    short8 Gh0 = *(const short8*)&ghi[((0 + wv) << 6 | lane) << 3];
    short8 Gl0 = *(const short8*)&glo[((0 + wv) << 6 | lane) << 3];
    short8 Gh1 = *(const short8*)&ghi[((4 + wv) << 6 | lane) << 3];
    short8 Gl1 = *(const short8*)&glo[((4 + wv) << 6 | lane) << 3];

    // ---- prefetch next-t hg rows (latency hides under MFMAs) --------------
    if (t + 1 < Bb) {
      const float* hg = hgAll + (size_t)(t + 1) * ((size_t)Mm * Hh);
#pragma unroll
      for (int it = 0; it < 2; ++it) {
        int task = (it << 8) + tid;
        int row = task >> 3, cOct = task & 7;
        const float* srcg = hg + ((m0 + row) << 6) + (cOct << 3);
        pa[it] = *(const float4*)srcg;
        pb[it] = *(const float4*)(srcg + 4);
      }
    }

    // ---- P frags: intra-wave transpose of this wave's OWN cbuf rows -------
    short8 Ph0{}, Pl0{}, Ph1{}, Pl1{};
    if (t) {
      const float* cb = &cbuf[((wv << 4) + (lane & 15)) * CST + ((lane >> 4) << 3)];
      float4 p00 = *(const float4*)cb;
      float4 p01 = *(const float4*)(cb + 4);
      float4 p10 = *(const float4*)(cb + 32);
      float4 p11 = *(const float4*)(cb + 36);
      float v0[8] = {p00.x, p00.y, p00.z, p00.w, p01.x, p01.y, p01.z, p01.w};
      float v1[8] = {p10.x, p10.y, p10.z, p10.w, p11.x, p11.y, p11.z, p11.w};
#pragma unroll
      for (int j = 0; j < 8; ++j) {
        unsigned short hs, ls;
        split_bf16(v0[j], hs, ls);
        Ph0[j] = (short)hs; Pl0[j] = (short)ls;
        split_bf16(v1[j], hs, ls);
        Ph1[j] = (short)hs; Pl1[j] = (short)ls;
      }
    }

    // ---- MFMA: gi (and gh for t>0), weights from LDS ----------------------
    f32x4 accR[4], accZ[4], accN[4], accH[4];
#pragma unroll
    for (int ct = 0; ct < 4; ++ct) {
      accR[ct] = (f32x4){biasR[ct], biasR[ct], biasR[ct], biasR[ct]};
      accZ[ct] = (f32x4){biasZ[ct], biasZ[ct], biasZ[ct], biasZ[ct]};
      accN[ct] = (f32x4){biasN[ct], biasN[ct], biasN[ct], biasN[ct]};
      accH[ct] = (f32x4){biasH[ct], biasH[ct], biasH[ct], biasH[ct]};
    }
#pragma unroll
    for (int ct = 0; ct < 4; ++ct) {
      mm6l(accR[ct], Gh0, Gl0, Gh1, Gl1, whi, wlo, 0 + ct, lane);
      mm6l(accZ[ct], Gh0, Gl0, Gh1, Gl1, whi, wlo, 4 + ct, lane);
      mm6l(accN[ct], Gh0, Gl0, Gh1, Gl1, whi, wlo, 8 + ct, lane);
    }
    if (t) {
#pragma unroll
      for (int ct = 0; ct < 4; ++ct) {
        mm6l(accR[ct], Ph0, Pl0, Ph1, Pl1, whi, wlo, 12 + ct, lane);
        mm6l(accZ[ct], Ph0, Pl0, Ph1, Pl1, whi, wlo, 16 + ct, lane);
        mm6l(accH[ct], Ph0, Pl0, Ph1, Pl1, whi, wlo, 20 + ct, lane);
      }
    }

    // ---- gates + h → cbuf (h_prev read from cbuf in place) ----------------
#pragma unroll
    for (int ct = 0; ct < 4; ++ct) {
#pragma unroll
      for (int r = 0; r < 4; ++r) {
        float rgate = sigf(accR[ct][r]);
        float zg = sigf(accZ[ct][r]);
        float ng = tanhfast(accN[ct][r] + rgate * accH[ct][r]);
        int ci = (rbase + r) * CST + (ct << 4) + nl;
        float hp = t ? cbuf[ci] : 0.f;
        cbuf[ci] = (1.f - zg) * ng + zg * hp;
      }
    }
    __syncthreads();   // C: cbuf complete for all 64 rows

    // ---- write h_out (coalesced) ------------------------------------------
    float* hout = houtAll + (size_t)t * ((size_t)Mm * Hh);
#pragma unroll
    for (int i = 0; i < 4; ++i) {
      int idx = (i << 10) + (tid << 2);
      int row = idx >> 6, col = idx & 63;
      *(float4*)(hout + ((m0 + row) << 6) + col) = *(float4*)&cbuf[row * CST + col];
    }
    // Loop seam: next-t ghi writes happen after this wave passed C (all other
    // waves' ghi reads done before C). cbuf: hout reads (here, pre-A) vs
    // next-t gates writes (post-A) ordered by A; P-frag reads and gates
    // writes are intra-wave (own rows only) and ordered by data dependence.
  }
}

// ---------------------------------------------------------------------------
// Heads v2 (R17, measured good).
// ---------------------------------------------------------------------------
__global__ __launch_bounds__(256) void k_heads(
    const float* __restrict__ Xb,
    const float* __restrict__ oW1, const float* __restrict__ ob1,
    const float* __restrict__ oW2, const float* __restrict__ ob2,
    const float* __restrict__ dW1, const float* __restrict__ db1,
    const float* __restrict__ dW2, const float* __restrict__ db2,
    float* __restrict__ out) {
  __shared__ float xa[64 * 65];
  __shared__ float w1o[64 * 32], w1d[64 * 32];
  __shared__ float po[4][64], pd[4][64];
  int tid = threadIdx.x;
  int rblk = blockIdx.x << 6;
  int b = rblk >> 11;
  int n0 = rblk & (Nn - 1);
  const float* src = Xb + (((size_t)b * Ss + (Ss - 1)) * Nn + n0) * Hh;
#pragma unroll
  for (int i = 0; i < 4; ++i) {
    int idx = (i << 10) + (tid << 2);
    int row = idx >> 6, col = idx & 63;
    float4 v = *(const float4*)(src + idx);
    float* dp = &xa[row * 65 + col];
    dp[0] = v.x; dp[1] = v.y; dp[2] = v.z; dp[3] = v.w;
  }
  for (int idx = tid; idx < 2048; idx += 256) {
    w1o[idx] = oW1[idx];
    w1d[idx] = dW1[idx];
  }
  __syncthreads();
  int row = tid & 63;
  int jg = tid >> 6;
  int j0 = jg << 3;
  float hO[8], hD[8];
#pragma unroll
  for (int j = 0; j < 8; ++j) { hO[j] = ob1[j0 + j]; hD[j] = db1[j0 + j]; }
  const float* xr = &xa[row * 65];
  for (int k = 0; k < 64; ++k) {
    float xv = xr[k];
    const float4* wo = (const float4*)&w1o[(k << 5) + j0];
    const float4* wd = (const float4*)&w1d[(k << 5) + j0];
    float4 o0 = wo[0], o1 = wo[1], d0 = wd[0], d1 = wd[1];
    hO[0] = fmaf(xv, o0.x, hO[0]); hO[1] = fmaf(xv, o0.y, hO[1]);
    hO[2] = fmaf(xv, o0.z, hO[2]); hO[3] = fmaf(xv, o0.w, hO[3]);
    hO[4] = fmaf(xv, o1.x, hO[4]); hO[5] = fmaf(xv, o1.y, hO[5]);
    hO[6] = fmaf(xv, o1.z, hO[6]); hO[7] = fmaf(xv, o1.w, hO[7]);
    hD[0] = fmaf(xv, d0.x, hD[0]); hD[1] = fmaf(xv, d0.y, hD[1]);
    hD[2] = fmaf(xv, d0.z, hD[2]); hD[3] = fmaf(xv, d0.w, hD[3]);
    hD[4] = fmaf(xv, d1.x, hD[4]); hD[5] = fmaf(xv, d1.y, hD[5]);
    hD[6] = fmaf(xv, d1.z, hD[6]); hD[7] = fmaf(xv, d1.w, hD[7]);
  }
  float accoP = 0.f, accdP = 0.f;
#pragma unroll
  for (int j = 0; j < 8; ++j) {
    accoP = fmaf(fmaxf(hO[j], 0.f), oW2[j0 + j], accoP);
    accdP = fmaf(fmaxf(hD[j], 0.f), dW2[j0 + j], accdP);
  }
  po[jg][row] = accoP;
  pd[jg][row] = accdP;
  __syncthreads();
  if (tid < 64) {
    int r = rblk + tid;
    out[r]           = ob2[0] + ((po[0][tid] + po[1][tid]) + (po[2][tid] + po[3][tid]));
    out[Bb * Nn + r] = db2[0] + ((pd[0][tid] + pd[1][tid]) + (pd[2][tid] + pd[3][tid]));
  }
}

// ---------------------------------------------------------------------------
extern "C" void kernel_launch(void* const* d_in, const int* in_sizes, int n_in,
                              void* d_out, int out_size, void* d_ws, size_t ws_size,
                              hipStream_t stream) {
  const float* x   = (const float*)d_in[0];
  const int*   ei  = (const int*)d_in[1];
  const float* ea  = (const float*)d_in[2];
  const float* Wp  = (const float*)d_in[3];
  const float* bp  = (const float*)d_in[4];
  const float* Wl  = (const float*)d_in[5];
  const float* bl  = (const float*)d_in[6];
  const float* Wr  = (const float*)d_in[7];
  const float* br  = (const float*)d_in[8];
  const float* We  = (const float*)d_in[9];
  const float* att = (const float*)d_in[10];
  const float* gb  = (const float*)d_in[11];
  const float* Wih = (const float*)d_in[12];
  const float* Whh = (const float*)d_in[13];
  const float* bih = (const float*)d_in[14];
  const float* bhh = (const float*)d_in[15];
  const float* oW1 = (const float*)d_in[16];
  const float* ob1 = (const float*)d_in[17];
  const float* oW2 = (const float*)d_in[18];
  const float* ob2 = (const float*)d_in[19];
  const float* dW1 = (const float*)d_in[20];
  const float* db1 = (const float*)d_in[21];
  const float* dW2 = (const float*)d_in[22];
  const float* db2 = (const float*)d_in[23];
  float* out = (float*)d_out;

  // workspace layout
  float* f    = (float*)d_ws;
  float* Xb   = f;                          // RTOT*64
  float* XLb  = Xb  + (size_t)RTOT * Hh;
  float* XRb  = XLb + (size_t)RTOT * Hh;    // hg after k_gat
  float* EPc  = XRb + (size_t)RTOT * Hh;    // 2 * E2c * 64 (CSR order, both layers)
  unsigned short* WXhi = (unsigned short*)(EPc + (size_t)2 * E2c * Hh); // 16384
  unsigned short* WXlo = WXhi + 16384;
  unsigned short* WGhi = WXlo + 16384;      // 49152
  unsigned short* WGlo = WGhi + 49152;
  float* cntF = (float*)(WGlo + 49152);     // 2048
  float* loopA = cntF + Nn;                 // 2048*8
  int*   fillI = (int*)(loopA + Nn * EFf);  // 2048
  int*   offs  = fillI + Nn;                // 2049 (+pad)
  int*   posOf = offs + 2052;               // 18432
  int*   srcA  = posOf + E2c;               // 18432

  hipMemsetAsync(cntF, 0, (size_t)(Nn + Nn * EFf + Nn) * 4, stream);

  k_loop_accum<<<dim3(Ee * EFf / 256), 256, 0, stream>>>(ei, ea, cntF, loopA);
  k_scan<<<1, 256, 0, stream>>>(cntF, offs);
  k_scatter<<<dim3((E2c + 255) / 256), 256, 0, stream>>>(ei, offs, fillI, posOf, srcA);
  k_wprep<<<dim3(256), 256, 0, stream>>>(Wl, Wr, Wih, Whh, WXhi, WXlo, WGhi, WGlo);

  // X = x @ Wp + bp
  k_proj<<<dim3(RTOT / 512, 4), 256, 0, stream>>>(x, Wp, bp, Xb);

  // ep for both layers (division by cnt folded in)
  k_ep<<<dim3(E2c * Hh / 256, 2), 256, 0, stream>>>(ea, loopA, We, posOf, cntF, EPc);

  for (int l = 0; l < 2; ++l) {
    k_xlr_mm<<<dim3(RTOT / 64), 256, 0, stream>>>(
        Xb, WXhi + (size_t)l * 8192, WXlo + (size_t)l * 8192,
        bl + (size_t)l * Hh, br + (size_t)l * Hh, XLb, XRb);
    k_gat<<<dim3(Nn, 4), 256, 0, stream>>>(
        XLb, XRb, EPc + (size_t)l * E2c * Hh, offs, srcA,
        att + (size_t)l * Hh, gb + (size_t)l * Hh);
    k_gru_fused<<<dim3(Mm / 64), 256, 0, stream>>>(
        XRb, WGhi + (size_t)l * 24576, WGlo + (size_t)l * 24576,
        bih + (size_t)l * 192, bhh + (size_t)l * 192, Xb);
  }

  k_heads<<<dim3(Bb * Nn / 64), 256, 0, stream>>>(
      Xb, oW1, ob1, oW2, ob2, dW1, db1, dW2, db2, out);
}

// Round 7
// 374.700 us; speedup vs baseline: 1.3758x; 1.0560x over previous
//
#include <hip/hip_runtime.h>
#include <math.h>

#define Bb   4
#define Ss   16
#define Nn   2048
#define Ff   32
#define Ee   16384
#define EFf  8
#define Hh   64
#define HB2  32
#define E2c  (Ee + Nn)          // 18432
#define RTOT (Bb*Ss*Nn)         // 131072 (64 graphs x 2048)
#define Mm   (Ss*Nn)            // 32768
#define CST  68                 // cbuf row stride (64 cols + pad)

typedef __attribute__((ext_vector_type(8))) short short8;
typedef __attribute__((ext_vector_type(4))) float f32x4;
#define MFMA16 __builtin_amdgcn_mfma_f32_16x16x32_bf16

__device__ __forceinline__ float sigf(float x) { return 1.f / (1.f + __expf(-x)); }
__device__ __forceinline__ float tanhfast(float x) { return 2.f / (1.f + __expf(-2.f * x)) - 1.f; }

__device__ __forceinline__ void split_bf16(float x, unsigned short& h, unsigned short& l) {
  unsigned u = __float_as_uint(x);
  unsigned r = (u + 0x7FFFu + ((u >> 16) & 1u)) >> 16;
  h = (unsigned short)r;
  float rest = x - __uint_as_float(r << 16);
  unsigned u2 = __float_as_uint(rest);
  l = (unsigned short)((u2 + 0x7FFFu + ((u2 >> 16) & 1u)) >> 16);
}

template <int PAT>
__device__ __forceinline__ float xorf(float v) {
  return __int_as_float(__builtin_amdgcn_ds_swizzle(__float_as_int(v), PAT));
}
__device__ __forceinline__ float red8(float v) {
  int x = __builtin_amdgcn_update_dpp(0, __float_as_int(v), 0x128, 0xF, 0xF, true);
  v += __int_as_float(x);
  v += xorf<0x401F>(v);
  v += __shfl_xor(v, 32, 64);
  return v;
}
__device__ __forceinline__ float redlogit(float v) {
  int x;
  x = __builtin_amdgcn_update_dpp(0, __float_as_int(v), 0xB1, 0xF, 0xF, true);
  v += __int_as_float(x);
  x = __builtin_amdgcn_update_dpp(0, __float_as_int(v), 0x4E, 0xF, 0xF, true);
  v += __int_as_float(x);
  v += xorf<0x101F>(v);
  return v;
}

// ---------------------------------------------------------------------------
__global__ __launch_bounds__(256) void k_loop_accum(
    const int* __restrict__ ei, const float* __restrict__ ea,
    float* __restrict__ cntF, float* __restrict__ loopA) {
  int idx = blockIdx.x * 256 + threadIdx.x;
  int e = idx >> 3, j = idx & 7;
  int d = ei[Ee + e];
  atomicAdd(&loopA[d * EFf + j], ea[idx]);
  if (j == 0) atomicAdd(&cntF[d], 1.0f);
}

// ---------------------------------------------------------------------------
__global__ __launch_bounds__(256) void k_scan(
    const float* __restrict__ cntF, int* __restrict__ offs) {
  __shared__ int partial[256];
  int tid = threadIdx.x;
  int base = tid * 8;
  int vals[8];
  int s = 0;
  for (int i = 0; i < 8; ++i) {
    int c = (int)cntF[base + i] + 1;
    vals[i] = c;
    s += c;
  }
  partial[tid] = s;
  __syncthreads();
  for (int off = 1; off < 256; off <<= 1) {
    int v = partial[tid];
    int add = (tid >= off) ? partial[tid - off] : 0;
    __syncthreads();
    partial[tid] = v + add;
    __syncthreads();
  }
  int run = (tid == 0) ? 0 : partial[tid - 1];
  for (int i = 0; i < 8; ++i) {
    offs[base + i] = run;
    run += vals[i];
  }
  if (tid == 255) offs[Nn] = run;
}

__global__ __launch_bounds__(256) void k_scatter(
    const int* __restrict__ ei, const int* __restrict__ offs,
    int* __restrict__ fillI, int* __restrict__ posOf, int* __restrict__ srcA) {
  int e = blockIdx.x * 256 + threadIdx.x;
  if (e >= E2c) return;
  int d = (e < Ee) ? ei[Ee + e] : (e - Ee);
  int s = (e < Ee) ? ei[e]      : (e - Ee);
  int pos = offs[d] + atomicAdd(&fillI[d], 1);
  posOf[e] = pos;
  srcA[pos] = s;
}

// ---------------------------------------------------------------------------
// Pre-split + pre-swizzle weights into MFMA B-fragment order (R9 layout).
// ---------------------------------------------------------------------------
__global__ __launch_bounds__(256) void k_wprep(
    const float* __restrict__ Wl, const float* __restrict__ Wr,
    const float* __restrict__ Wih, const float* __restrict__ Whh,
    unsigned short* __restrict__ WXhi, unsigned short* __restrict__ WXlo,
    unsigned short* __restrict__ WGhi, unsigned short* __restrict__ WGlo) {
  int idx = blockIdx.x * 256 + threadIdx.x;   // 65536 total
  if (idx < 16384) {
    int j = idx & 7, lane = (idx >> 3) & 63, kh = (idx >> 9) & 1;
    int t = (idx >> 10) & 7, l = idx >> 13;
    int n = t * 16 + (lane & 15);
    int k = kh * 32 + ((lane >> 4) << 3) + j;
    const float* W = (n < 64) ? (Wl + (size_t)l * 4096) : (Wr + (size_t)l * 4096);
    float v = W[k * 64 + (n & 63)];
    unsigned short h, lo;
    split_bf16(v, h, lo);
    WXhi[idx] = h; WXlo[idx] = lo;
  } else {
    int i2 = idx - 16384;                     // < 49152
    int j = i2 & 7, lane = (i2 >> 3) & 63, kh = (i2 >> 9) & 1;
    int t = (i2 >> 10) % 24, l = i2 / 24576;
    int n = t * 16 + (lane & 15);
    int k = kh * 32 + ((lane >> 4) << 3) + j;
    int g = n >> 6, c = n & 63;
    const float* W = (g < 3) ? (Wih + (size_t)l * 12288 + (size_t)(g * 64 + c) * 64)
                             : (Whh + (size_t)l * 12288 + (size_t)((g - 3) * 64 + c) * 64);
    float v = W[k];
    unsigned short h, lo;
    split_bf16(v, h, lo);
    WGhi[i2] = h; WGlo[i2] = lo;
  }
}

// ---------------------------------------------------------------------------
// ep for BOTH layers; self-loop mean division folded in. blockIdx.y = layer.
// ---------------------------------------------------------------------------
__global__ __launch_bounds__(256) void k_ep(
    const float* __restrict__ ea, const float* __restrict__ loopA,
    const float* __restrict__ We, const int* __restrict__ posOf,
    const float* __restrict__ cntF, float* __restrict__ EPc) {
  __shared__ float wlds[EFf * Hh];
  int tid = threadIdx.x;
  int l = blockIdx.y;
  const float* Wel = We + (size_t)l * EFf * Hh;
  if (tid < EFf * Hh) wlds[tid] = Wel[tid];
  if (tid + 256 < EFf * Hh) wlds[tid + 256] = Wel[tid + 256];
  __syncthreads();
  int idx = blockIdx.x * 256 + tid;
  int e = idx >> 6, j = idx & 63;
  const float* a = (e < Ee) ? (ea + (size_t)e * EFf) : (loopA + (size_t)(e - Ee) * EFf);
  float acc = 0.f;
#pragma unroll
  for (int k = 0; k < EFf; ++k) acc += a[k] * wlds[k * Hh + j];
  if (e >= Ee) acc /= fmaxf(cntF[e - Ee], 1.0f);
  EPc[(size_t)l * E2c * Hh + (((size_t)posOf[e]) << 6) + j] = acc;
}

// ---------------------------------------------------------------------------
// proj (R5 version): thread = 2 rows x 16 cols. grid (RTOT/512, 4)
// ---------------------------------------------------------------------------
__global__ __launch_bounds__(256) void k_proj(
    const float* __restrict__ X, const float* __restrict__ Wp,
    const float* __restrict__ bp, float* __restrict__ Out) {
  __shared__ float w[32 * 16];
  int tid = threadIdx.x;
  int j0 = blockIdx.y << 4;
  for (int idx = tid; idx < 32 * 16; idx += 256)
    w[idx] = Wp[((idx >> 4) << 6) + j0 + (idx & 15)];
  __syncthreads();
  int r0 = (blockIdx.x << 9) + tid;
  float acc[2][16];
#pragma unroll
  for (int jj = 0; jj < 16; ++jj) { float b = bp[j0 + jj]; acc[0][jj] = b; acc[1][jj] = b; }
  const float* x0 = X + ((size_t)r0 << 5);
  const float* x1 = x0 + (256 << 5);
  for (int kc = 0; kc < 8; ++kc) {
    float4 a0 = *(const float4*)(x0 + 4 * kc);
    float4 a1 = *(const float4*)(x1 + 4 * kc);
    float a0a[4] = {a0.x, a0.y, a0.z, a0.w};
    float a1a[4] = {a1.x, a1.y, a1.z, a1.w};
#pragma unroll
    for (int q = 0; q < 4; ++q) {
      const float4* wp4 = (const float4*)(w + ((4 * kc + q) << 4));
#pragma unroll
      for (int q4 = 0; q4 < 4; ++q4) {
        float4 wv = wp4[q4];
        acc[0][4*q4+0] = fmaf(a0a[q], wv.x, acc[0][4*q4+0]);
        acc[0][4*q4+1] = fmaf(a0a[q], wv.y, acc[0][4*q4+1]);
        acc[0][4*q4+2] = fmaf(a0a[q], wv.z, acc[0][4*q4+2]);
        acc[0][4*q4+3] = fmaf(a0a[q], wv.w, acc[0][4*q4+3]);
        acc[1][4*q4+0] = fmaf(a1a[q], wv.x, acc[1][4*q4+0]);
        acc[1][4*q4+1] = fmaf(a1a[q], wv.y, acc[1][4*q4+1]);
        acc[1][4*q4+2] = fmaf(a1a[q], wv.z, acc[1][4*q4+2]);
        acc[1][4*q4+3] = fmaf(a1a[q], wv.w, acc[1][4*q4+3]);
      }
    }
  }
#pragma unroll
  for (int rr = 0; rr < 2; ++rr) {
    float* op = Out + (((size_t)(r0 + 256 * rr)) << 6) + j0;
#pragma unroll
    for (int q4 = 0; q4 < 4; ++q4)
      *(float4*)(op + 4 * q4) = make_float4(acc[rr][4*q4], acc[rr][4*q4+1], acc[rr][4*q4+2], acc[rr][4*q4+3]);
  }
}

// ---------------------------------------------------------------------------
// XL/XR via bf16x3 MFMA (R14, measured good).
// ---------------------------------------------------------------------------
__global__ __launch_bounds__(256) void k_xlr_mm(
    const float* __restrict__ X,
    const unsigned short* __restrict__ WXhi, const unsigned short* __restrict__ WXlo,
    const float* __restrict__ bl_, const float* __restrict__ br_,
    float* __restrict__ XL, float* __restrict__ XR) {
  __shared__ unsigned short ahi[4096], alo[4096];
  __shared__ float cbuf[64 * CST];
  int tid = threadIdx.x, lane = tid & 63, wv = tid >> 6;
  size_t m0 = (size_t)blockIdx.x << 6;
#pragma unroll
  for (int it = 0; it < 2; ++it) {
    int task = (it << 8) + tid;
    int row = task >> 3, cOct = task & 7;
    const float* src = X + ((m0 + row) << 6) + (cOct << 3);
    float4 a = *(const float4*)src;
    float4 b = *(const float4*)(src + 4);
    float va[8] = {a.x, a.y, a.z, a.w, b.x, b.y, b.z, b.w};
    short8 hv, lv;
#pragma unroll
    for (int j = 0; j < 8; ++j) {
      unsigned short hs, ls;
      split_bf16(va[j], hs, ls);
      hv[j] = (short)hs; lv[j] = (short)ls;
    }
    int f = ((cOct >> 2) * 4 + (row >> 4)) * 64 + ((cOct & 3) << 4) + (row & 15);
    *(short8*)&ahi[f << 3] = hv;
    *(short8*)&alo[f << 3] = lv;
  }
  __syncthreads();
  short8 Ah0 = *(const short8*)&ahi[((0 + wv) << 6 | lane) << 3];
  short8 Al0 = *(const short8*)&alo[((0 + wv) << 6 | lane) << 3];
  short8 Ah1 = *(const short8*)&ahi[((4 + wv) << 6 | lane) << 3];
  short8 Al1 = *(const short8*)&alo[((4 + wv) << 6 | lane) << 3];
  int nl = lane & 15;
  f32x4 acc[8];
#pragma unroll
  for (int t = 0; t < 8; ++t) {
    int n = t * 16 + nl;
    float b = (n < 64) ? bl_[n] : br_[n - 64];
    acc[t] = (f32x4){b, b, b, b};
  }
#pragma unroll
  for (int t = 0; t < 8; ++t) {
    const short8* bh0p = (const short8*)(WXhi + ((t << 1) << 9)) + lane;
    const short8* bl0p = (const short8*)(WXlo + ((t << 1) << 9)) + lane;
    const short8* bh1p = (const short8*)(WXhi + (((t << 1) + 1) << 9)) + lane;
    const short8* bl1p = (const short8*)(WXlo + (((t << 1) + 1) << 9)) + lane;
    short8 bh0 = *bh0p, bl0 = *bl0p, bh1 = *bh1p, bl1 = *bl1p;
    acc[t] = MFMA16(Ah0, bh0, acc[t], 0, 0, 0);
    acc[t] = MFMA16(Ah0, bl0, acc[t], 0, 0, 0);
    acc[t] = MFMA16(Al0, bh0, acc[t], 0, 0, 0);
    acc[t] = MFMA16(Ah1, bh1, acc[t], 0, 0, 0);
    acc[t] = MFMA16(Ah1, bl1, acc[t], 0, 0, 0);
    acc[t] = MFMA16(Al1, bh1, acc[t], 0, 0, 0);
  }
  int rbase = (wv << 4) + ((lane >> 4) << 2);
#pragma unroll
  for (int half = 0; half < 2; ++half) {
    __syncthreads();
#pragma unroll
    for (int tt = 0; tt < 4; ++tt) {
      int t = (half << 2) + tt;
#pragma unroll
      for (int reg = 0; reg < 4; ++reg)
        cbuf[(rbase + reg) * CST + (tt << 4) + nl] = acc[t][reg];
    }
    __syncthreads();
    float* dst = half ? XR : XL;
#pragma unroll
    for (int i = 0; i < 4; ++i) {
      int idx = (i << 10) + (tid << 2);
      int row = idx >> 6, col = idx & 63;
      *(float4*)(dst + ((m0 + row) << 6) + col) = *(float4*)&cbuf[row * CST + col];
    }
  }
}

// ---------------------------------------------------------------------------
// GATv2 v7: block = (dst d, graph 16-group q). Wave handles 4 graphs
// (q*16+wv+4c). EP/srcA loads amortized over 4 chains; ~10 VMEM in flight.
// grid (Nn, 4).
// ---------------------------------------------------------------------------
__global__ __launch_bounds__(256) void k_gat(
    const float* __restrict__ XL, float* __restrict__ XR_HG,
    const float* __restrict__ EPc, const int* __restrict__ offs,
    const int* __restrict__ srcA,
    const float* __restrict__ att, const float* __restrict__ gbl) {
  int d = blockIdx.x;
  int q = blockIdx.y;
  int tid = threadIdx.x;
  int wv = tid >> 6, lane = tid & 63;
  int eSub = lane >> 3, hOct = lane & 7;
  int hb = hOct << 3;
  float at[8], gv[8];
  {
    float4 a0 = *(const float4*)(att + hb);
    float4 a1 = *(const float4*)(att + hb + 4);
    float4 g0v = *(const float4*)(gbl + hb);
    float4 g1v = *(const float4*)(gbl + hb + 4);
    at[0]=a0.x; at[1]=a0.y; at[2]=a0.z; at[3]=a0.w;
    at[4]=a1.x; at[5]=a1.y; at[6]=a1.z; at[7]=a1.w;
    gv[0]=g0v.x; gv[1]=g0v.y; gv[2]=g0v.z; gv[3]=g0v.w;
    gv[4]=g1v.x; gv[5]=g1v.y; gv[6]=g1v.z; gv[7]=g1v.w;
  }
  int p0 = offs[d], p1 = offs[d + 1];
  int nE = p1 - p0;
  int nCh = (nE + 7) >> 3;
  int gbase = (q << 4) + wv;
  size_t rowg[4];
  const float* Xg[4];
  float xr[4][8];
#pragma unroll
  for (int c = 0; c < 4; ++c) {
    int g = gbase + (c << 2);
    rowg[c] = ((size_t)(g * Nn + d)) << 6;
    Xg[c] = XL + (((size_t)g * Nn) << 6);
    float4 a = *(const float4*)(XR_HG + rowg[c] + hb);
    float4 b = *(const float4*)(XR_HG + rowg[c] + hb + 4);
    xr[c][0]=a.x; xr[c][1]=a.y; xr[c][2]=a.z; xr[c][3]=a.w;
    xr[c][4]=b.x; xr[c][5]=b.y; xr[c][6]=b.z; xr[c][7]=b.w;
  }
  float Sd[4] = {0.f, 0.f, 0.f, 0.f};
  float acc[4][8];
#pragma unroll
  for (int c = 0; c < 4; ++c)
#pragma unroll
    for (int j = 0; j < 8; ++j) acc[c][j] = 0.f;

  for (int ck = 0; ck < nCh; ++ck) {
    int p = (ck << 3) + eSub;
    int pc = p < nE ? p : nE - 1;
    int s = srcA[p0 + pc];
    const float* epp = EPc + (((size_t)(p0 + pc)) << 6) + hb;
    float4 e0 = *(const float4*)epp;
    float4 e1 = *(const float4*)(epp + 4);
    float ep[8] = {e0.x, e0.y, e0.z, e0.w, e1.x, e1.y, e1.z, e1.w};
    float xlv[4][8];
#pragma unroll
    for (int c = 0; c < 4; ++c) {
      const float* xp = Xg[c] + ((size_t)s << 6) + hb;
      float4 x0 = *(const float4*)xp;
      float4 x1 = *(const float4*)(xp + 4);
      xlv[c][0]=x0.x; xlv[c][1]=x0.y; xlv[c][2]=x0.z; xlv[c][3]=x0.w;
      xlv[c][4]=x1.x; xlv[c][5]=x1.y; xlv[c][6]=x1.z; xlv[c][7]=x1.w;
    }
    float v[4] = {0.f, 0.f, 0.f, 0.f};
#pragma unroll
    for (int c = 0; c < 4; ++c)
#pragma unroll
      for (int j = 0; j < 8; ++j) {
        float m = xlv[c][j] + xr[c][j] + ep[j];
        m = fmaxf(m, 0.2f * m);
        v[c] = fmaf(m, at[j], v[c]);
      }
#pragma unroll
    for (int c = 0; c < 4; ++c) v[c] = redlogit(v[c]);
    bool live = (p < nE);
#pragma unroll
    for (int c = 0; c < 4; ++c) {
      float w = live ? __expf(v[c]) : 0.f;
      Sd[c] += w;
#pragma unroll
      for (int j = 0; j < 8; ++j) acc[c][j] = fmaf(w, xlv[c][j], acc[c][j]);
    }
  }
#pragma unroll
  for (int c = 0; c < 4; ++c) {
    Sd[c] = red8(Sd[c]);
#pragma unroll
    for (int j = 0; j < 8; ++j) acc[c][j] = red8(acc[c][j]);
  }
  if (eSub == 0) {
#pragma unroll
    for (int c = 0; c < 4; ++c) {
      float inv = 1.f / Sd[c];
      float* op = XR_HG + rowg[c] + hb;
      *(float4*)(op)     = make_float4(fmaf(acc[c][0], inv, gv[0]), fmaf(acc[c][1], inv, gv[1]),
                                       fmaf(acc[c][2], inv, gv[2]), fmaf(acc[c][3], inv, gv[3]));
      *(float4*)(op + 4) = make_float4(fmaf(acc[c][4], inv, gv[4]), fmaf(acc[c][5], inv, gv[5]),
                                       fmaf(acc[c][6], inv, gv[6]), fmaf(acc[c][7], inv, gv[7]));
    }
  }
}

// ---------------------------------------------------------------------------
// Fused GRU v5: wave-owns-column-tile, weights in REGISTERS.
// v4's limiter was LDS read traffic (~100 ds_read_b128/wave/t on one LDS
// port) + 1 block/CU (129 KB LDS). v5: wave wv owns gate-column tile ct=wv
// and holds its 24 weight fragments (96 VGPR) for the whole kernel — loaded
// from L2 once. Per row-tile rg it reads only G/P fragments (8 b128) and
// runs 36 MFMAs. LDS: ghi/glo + cbuf = 33 KB -> 2 blocks/CU, 512 blocks all
// resident. Barriers A (staging), B (P-reads before cbuf overwrite), C
// (gates done) per t.
// ---------------------------------------------------------------------------
__device__ __forceinline__ void mm6r(f32x4& acc,
    short8 Ah0, short8 Al0, short8 Ah1, short8 Al1,
    short8 bh0, short8 bl0, short8 bh1, short8 bl1) {
  acc = MFMA16(Ah0, bh0, acc, 0, 0, 0);
  acc = MFMA16(Ah0, bl0, acc, 0, 0, 0);
  acc = MFMA16(Al0, bh0, acc, 0, 0, 0);
  acc = MFMA16(Ah1, bh1, acc, 0, 0, 0);
  acc = MFMA16(Ah1, bl1, acc, 0, 0, 0);
  acc = MFMA16(Al1, bh1, acc, 0, 0, 0);
}

__global__ __launch_bounds__(256, 2) void k_gru_fused(
    const float* __restrict__ hgAll,
    const unsigned short* __restrict__ WGhi, const unsigned short* __restrict__ WGlo,
    const float* __restrict__ bih, const float* __restrict__ bhh,
    float* __restrict__ houtAll) {
  __shared__ unsigned short ghi[4096], glo[4096];     // 16 KB input frags
  __shared__ float cbuf[64 * CST];                    // 17 KB h / output stage
  int tid = threadIdx.x, lane = tid & 63, wv = tid >> 6;
  int nl = lane & 15;
  int rb0 = (lane >> 4) << 2;
  size_t m0 = (size_t)blockIdx.x << 6;

  // ---- per-wave weight fragments in registers: gate-col tile ct = wv ------
  // tt set = {wv, wv+4, wv+8} (G: R,Z,N) + {wv+12, wv+16, wv+20} (P: R,Z,H)
  short8 Wh[6][2], Wl[6][2];
#pragma unroll
  for (int g = 0; g < 6; ++g) {
    int tt = wv + (g << 2);
    Wh[g][0] = *((const short8*)(WGhi + (tt << 10)) + lane);
    Wh[g][1] = *((const short8*)(WGhi + (tt << 10) + 512) + lane);
    Wl[g][0] = *((const short8*)(WGlo + (tt << 10)) + lane);
    Wl[g][1] = *((const short8*)(WGlo + (tt << 10) + 512) + lane);
  }

  // biases for this wave's 16 columns (c = wv*16 + nl)
  float biasR, biasZ, biasN, biasH;
  {
    int c = (wv << 4) + nl;
    biasR = bih[c]       + bhh[c];
    biasZ = bih[64 + c]  + bhh[64 + c];
    biasN = bih[128 + c];
    biasH = bhh[128 + c];
  }

  // t=0 prefetch: 512 row-octet tasks / 256 thr = 2 its
  float4 pa[2], pb[2];
#pragma unroll
  for (int it = 0; it < 2; ++it) {
    int task = (it << 8) + tid;
    int row = task >> 3, cOct = task & 7;
    const float* srcg = hgAll + ((m0 + row) << 6) + (cOct << 3);
    pa[it] = *(const float4*)srcg;
    pb[it] = *(const float4*)(srcg + 4);
  }

  for (int t = 0; t < Bb; ++t) {
    // ---- stage G (from prefetched regs) → ghi/glo -------------------------
#pragma unroll
    for (int it = 0; it < 2; ++it) {
      int task = (it << 8) + tid;
      int row = task >> 3, cOct = task & 7;
      float va[8] = {pa[it].x, pa[it].y, pa[it].z, pa[it].w,
                     pb[it].x, pb[it].y, pb[it].z, pb[it].w};
      short8 hv8, lv8;
#pragma unroll
      for (int j = 0; j < 8; ++j) {
        unsigned short hs, ls;
        split_bf16(va[j], hs, ls);
        hv8[j] = (short)hs; lv8[j] = (short)ls;
      }
      int f = ((cOct >> 2) * 4 + (row >> 4)) * 64 + ((cOct & 3) << 4) + (row & 15);
      *(short8*)&ghi[f << 3] = hv8;
      *(short8*)&glo[f << 3] = lv8;
    }
    __syncthreads();   // A: ghi/glo ready; prev cbuf stable for P reads

    // ---- prefetch next-t hg rows (latency hides under MFMAs) --------------
    if (t + 1 < Bb) {
      const float* hg = hgAll + (size_t)(t + 1) * ((size_t)Mm * Hh);
#pragma unroll
      for (int it = 0; it < 2; ++it) {
        int task = (it << 8) + tid;
        int row = task >> 3, cOct = task & 7;
        const float* srcg = hg + ((m0 + row) << 6) + (cOct << 3);
        pa[it] = *(const float4*)srcg;
        pb[it] = *(const float4*)(srcg + 4);
      }
    }

    // ---- MFMA over 4 row-tiles; this wave computes its column tile --------
    f32x4 accR[4], accZ[4], accN[4], accH[4];
#pragma unroll
    for (int rg = 0; rg < 4; ++rg) {
      accR[rg] = (f32x4){biasR, biasR, biasR, biasR};
      accZ[rg] = (f32x4){biasZ, biasZ, biasZ, biasZ};
      accN[rg] = (f32x4){biasN, biasN, biasN, biasN};
      accH[rg] = (f32x4){biasH, biasH, biasH, biasH};
    }
#pragma unroll
    for (int rg = 0; rg < 4; ++rg) {
      short8 Gh0 = *(const short8*)&ghi[((0 + rg) << 6 | lane) << 3];
      short8 Gl0 = *(const short8*)&glo[((0 + rg) << 6 | lane) << 3];
      short8 Gh1 = *(const short8*)&ghi[((4 + rg) << 6 | lane) << 3];
      short8 Gl1 = *(const short8*)&glo[((4 + rg) << 6 | lane) << 3];
      mm6r(accR[rg], Gh0, Gl0, Gh1, Gl1, Wh[0][0], Wl[0][0], Wh[0][1], Wl[0][1]);
      mm6r(accZ[rg], Gh0, Gl0, Gh1, Gl1, Wh[1][0], Wl[1][0], Wh[1][1], Wl[1][1]);
      mm6r(accN[rg], Gh0, Gl0, Gh1, Gl1, Wh[2][0], Wl[2][0], Wh[2][1], Wl[2][1]);
      if (t) {
        // P frags for row-tile rg: transpose-read prev h from cbuf
        const float* cb = &cbuf[((rg << 4) + (lane & 15)) * CST + ((lane >> 4) << 3)];
        float4 p00 = *(const float4*)cb;
        float4 p01 = *(const float4*)(cb + 4);
        float4 p10 = *(const float4*)(cb + 32);
        float4 p11 = *(const float4*)(cb + 36);
        float v0[8] = {p00.x, p00.y, p00.z, p00.w, p01.x, p01.y, p01.z, p01.w};
        float v1[8] = {p10.x, p10.y, p10.z, p10.w, p11.x, p11.y, p11.z, p11.w};
        short8 Ph0, Pl0, Ph1, Pl1;
#pragma unroll
        for (int j = 0; j < 8; ++j) {
          unsigned short hs, ls;
          split_bf16(v0[j], hs, ls);
          Ph0[j] = (short)hs; Pl0[j] = (short)ls;
          split_bf16(v1[j], hs, ls);
          Ph1[j] = (short)hs; Pl1[j] = (short)ls;
        }
        mm6r(accR[rg], Ph0, Pl0, Ph1, Pl1, Wh[3][0], Wl[3][0], Wh[3][1], Wl[3][1]);
        mm6r(accZ[rg], Ph0, Pl0, Ph1, Pl1, Wh[4][0], Wl[4][0], Wh[4][1], Wl[4][1]);
        mm6r(accH[rg], Ph0, Pl0, Ph1, Pl1, Wh[5][0], Wl[5][0], Wh[5][1], Wl[5][1]);
      }
    }
    __syncthreads();   // B: all P reads of prev cbuf done before overwrite

    // ---- gates + h → cbuf (h_prev blend reads own column in place) --------
#pragma unroll
    for (int rg = 0; rg < 4; ++rg) {
#pragma unroll
      for (int r = 0; r < 4; ++r) {
        float rgate = sigf(accR[rg][r]);
        float zg = sigf(accZ[rg][r]);
        float ng = tanhfast(accN[rg][r] + rgate * accH[rg][r]);
        int ci = ((rg << 4) + rb0 + r) * CST + (wv << 4) + nl;
        float hp = t ? cbuf[ci] : 0.f;
        cbuf[ci] = (1.f - zg) * ng + zg * hp;
      }
    }
    __syncthreads();   // C: cbuf complete for all 64 rows

    // ---- write h_out (coalesced) ------------------------------------------
    float* hout = houtAll + (size_t)t * ((size_t)Mm * Hh);
#pragma unroll
    for (int i = 0; i < 4; ++i) {
      int idx = (i << 10) + (tid << 2);
      int row = idx >> 6, col = idx & 63;
      *(float4*)(hout + ((m0 + row) << 6) + col) = *(float4*)&cbuf[row * CST + col];
    }
    // Seam: next-t ghi writes after all waves passed C (frag reads done in
    // rg loop before B). cbuf: hout reads (pre-A of next t) vs next gates
    // writes (post-B) ordered by next A/B; P reads (post-A) vs gates writes
    // (post-B) ordered by B.
  }
}

// ---------------------------------------------------------------------------
// Heads v2 (R17, measured good).
// ---------------------------------------------------------------------------
__global__ __launch_bounds__(256) void k_heads(
    const float* __restrict__ Xb,
    const float* __restrict__ oW1, const float* __restrict__ ob1,
    const float* __restrict__ oW2, const float* __restrict__ ob2,
    const float* __restrict__ dW1, const float* __restrict__ db1,
    const float* __restrict__ dW2, const float* __restrict__ db2,
    float* __restrict__ out) {
  __shared__ float xa[64 * 65];
  __shared__ float w1o[64 * 32], w1d[64 * 32];
  __shared__ float po[4][64], pd[4][64];
  int tid = threadIdx.x;
  int rblk = blockIdx.x << 6;
  int b = rblk >> 11;
  int n0 = rblk & (Nn - 1);
  const float* src = Xb + (((size_t)b * Ss + (Ss - 1)) * Nn + n0) * Hh;
#pragma unroll
  for (int i = 0; i < 4; ++i) {
    int idx = (i << 10) + (tid << 2);
    int row = idx >> 6, col = idx & 63;
    float4 v = *(const float4*)(src + idx);
    float* dp = &xa[row * 65 + col];
    dp[0] = v.x; dp[1] = v.y; dp[2] = v.z; dp[3] = v.w;
  }
  for (int idx = tid; idx < 2048; idx += 256) {
    w1o[idx] = oW1[idx];
    w1d[idx] = dW1[idx];
  }
  __syncthreads();
  int row = tid & 63;
  int jg = tid >> 6;
  int j0 = jg << 3;
  float hO[8], hD[8];
#pragma unroll
  for (int j = 0; j < 8; ++j) { hO[j] = ob1[j0 + j]; hD[j] = db1[j0 + j]; }
  const float* xr = &xa[row * 65];
  for (int k = 0; k < 64; ++k) {
    float xv = xr[k];
    const float4* wo = (const float4*)&w1o[(k << 5) + j0];
    const float4* wd = (const float4*)&w1d[(k << 5) + j0];
    float4 o0 = wo[0], o1 = wo[1], d0 = wd[0], d1 = wd[1];
    hO[0] = fmaf(xv, o0.x, hO[0]); hO[1] = fmaf(xv, o0.y, hO[1]);
    hO[2] = fmaf(xv, o0.z, hO[2]); hO[3] = fmaf(xv, o0.w, hO[3]);
    hO[4] = fmaf(xv, o1.x, hO[4]); hO[5] = fmaf(xv, o1.y, hO[5]);
    hO[6] = fmaf(xv, o1.z, hO[6]); hO[7] = fmaf(xv, o1.w, hO[7]);
    hD[0] = fmaf(xv, d0.x, hD[0]); hD[1] = fmaf(xv, d0.y, hD[1]);
    hD[2] = fmaf(xv, d0.z, hD[2]); hD[3] = fmaf(xv, d0.w, hD[3]);
    hD[4] = fmaf(xv, d1.x, hD[4]); hD[5] = fmaf(xv, d1.y, hD[5]);
    hD[6] = fmaf(xv, d1.z, hD[6]); hD[7] = fmaf(xv, d1.w, hD[7]);
  }
  float accoP = 0.f, accdP = 0.f;
#pragma unroll
  for (int j = 0; j < 8; ++j) {
    accoP = fmaf(fmaxf(hO[j], 0.f), oW2[j0 + j], accoP);
    accdP = fmaf(fmaxf(hD[j], 0.f), dW2[j0 + j], accdP);
  }
  po[jg][row] = accoP;
  pd[jg][row] = accdP;
  __syncthreads();
  if (tid < 64) {
    int r = rblk + tid;
    out[r]           = ob2[0] + ((po[0][tid] + po[1][tid]) + (po[2][tid] + po[3][tid]));
    out[Bb * Nn + r] = db2[0] + ((pd[0][tid] + pd[1][tid]) + (pd[2][tid] + pd[3][tid]));
  }
}

// ---------------------------------------------------------------------------
extern "C" void kernel_launch(void* const* d_in, const int* in_sizes, int n_in,
                              void* d_out, int out_size, void* d_ws, size_t ws_size,
                              hipStream_t stream) {
  const float* x   = (const float*)d_in[0];
  const int*   ei  = (const int*)d_in[1];
  const float* ea  = (const float*)d_in[2];
  const float* Wp  = (const float*)d_in[3];
  const float* bp  = (const float*)d_in[4];
  const float* Wl  = (const float*)d_in[5];
  const float* bl  = (const float*)d_in[6];
  const float* Wr  = (const float*)d_in[7];
  const float* br  = (const float*)d_in[8];
  const float* We  = (const float*)d_in[9];
  const float* att = (const float*)d_in[10];
  const float* gb  = (const float*)d_in[11];
  const float* Wih = (const float*)d_in[12];
  const float* Whh = (const float*)d_in[13];
  const float* bih = (const float*)d_in[14];
  const float* bhh = (const float*)d_in[15];
  const float* oW1 = (const float*)d_in[16];
  const float* ob1 = (const float*)d_in[17];
  const float* oW2 = (const float*)d_in[18];
  const float* ob2 = (const float*)d_in[19];
  const float* dW1 = (const float*)d_in[20];
  const float* db1 = (const float*)d_in[21];
  const float* dW2 = (const float*)d_in[22];
  const float* db2 = (const float*)d_in[23];
  float* out = (float*)d_out;

  // workspace layout
  float* f    = (float*)d_ws;
  float* Xb   = f;                          // RTOT*64
  float* XLb  = Xb  + (size_t)RTOT * Hh;
  float* XRb  = XLb + (size_t)RTOT * Hh;    // hg after k_gat
  float* EPc  = XRb + (size_t)RTOT * Hh;    // 2 * E2c * 64 (CSR order, both layers)
  unsigned short* WXhi = (unsigned short*)(EPc + (size_t)2 * E2c * Hh); // 16384
  unsigned short* WXlo = WXhi + 16384;
  unsigned short* WGhi = WXlo + 16384;      // 49152
  unsigned short* WGlo = WGhi + 49152;
  float* cntF = (float*)(WGlo + 49152);     // 2048
  float* loopA = cntF + Nn;                 // 2048*8
  int*   fillI = (int*)(loopA + Nn * EFf);  // 2048
  int*   offs  = fillI + Nn;                // 2049 (+pad)
  int*   posOf = offs + 2052;               // 18432
  int*   srcA  = posOf + E2c;               // 18432

  hipMemsetAsync(cntF, 0, (size_t)(Nn + Nn * EFf + Nn) * 4, stream);

  k_loop_accum<<<dim3(Ee * EFf / 256), 256, 0, stream>>>(ei, ea, cntF, loopA);
  k_scan<<<1, 256, 0, stream>>>(cntF, offs);
  k_scatter<<<dim3((E2c + 255) / 256), 256, 0, stream>>>(ei, offs, fillI, posOf, srcA);
  k_wprep<<<dim3(256), 256, 0, stream>>>(Wl, Wr, Wih, Whh, WXhi, WXlo, WGhi, WGlo);

  // X = x @ Wp + bp
  k_proj<<<dim3(RTOT / 512, 4), 256, 0, stream>>>(x, Wp, bp, Xb);

  // ep for both layers (division by cnt folded in)
  k_ep<<<dim3(E2c * Hh / 256, 2), 256, 0, stream>>>(ea, loopA, We, posOf, cntF, EPc);

  for (int l = 0; l < 2; ++l) {
    k_xlr_mm<<<dim3(RTOT / 64), 256, 0, stream>>>(
        Xb, WXhi + (size_t)l * 8192, WXlo + (size_t)l * 8192,
        bl + (size_t)l * Hh, br + (size_t)l * Hh, XLb, XRb);
    k_gat<<<dim3(Nn, 4), 256, 0, stream>>>(
        XLb, XRb, EPc + (size_t)l * E2c * Hh, offs, srcA,
        att + (size_t)l * Hh, gb + (size_t)l * Hh);
    k_gru_fused<<<dim3(Mm / 64), 256, 0, stream>>>(
        XRb, WGhi + (size_t)l * 24576, WGlo + (size_t)l * 24576,
        bih + (size_t)l * 192, bhh + (size_t)l * 192, Xb);
  }

  k_heads<<<dim3(Bb * Nn / 64), 256, 0, stream>>>(
      Xb, oW1, ob1, oW2, ob2, dW1, db1, dW2, db2, out);
}